// Round 3
// baseline (1285.461 us; speedup 1.0000x reference)
//
#include <hip/hip_runtime.h>
#include <math.h>

#define NPIXF 196608   // fine nodes (12*128*128)
#define NCC   49152    // coarse nodes (NPIXF/4)
// batch B=4, fine channels 2 -> T layout [N][B*2] = 8 floats (32B) per node

// ---------------------------------------------------------------------------
// transpose maps [B][N][2] -> xt [N][B][2]
__global__ __launch_bounds__(256) void k_transpose2(const float* __restrict__ maps,
                                                    float* __restrict__ xt) {
    int n = blockIdx.x * 256 + threadIdx.x;
    if (n >= NPIXF) return;
    const float2* m2 = (const float2*)maps;
    float2 v0 = m2[0 * NPIXF + n];
    float2 v1 = m2[1 * NPIXF + n];
    float2 v2 = m2[2 * NPIXF + n];
    float2 v3 = m2[3 * NPIXF + n];
    float4* o = (float4*)(xt + (size_t)n * 8);
    o[0] = make_float4(v0.x, v0.y, v1.x, v1.y);
    o[1] = make_float4(v2.x, v2.y, v3.x, v3.y);
}

// ---------------------------------------------------------------------------
// one Chebyshev/Laplacian step on the [N][8] layout.
// FIRST: dst = lap(src).   else: dst = 2*lap(src) - src2
template <int NN, bool FIRST>
__global__ __launch_bounds__(256) void k_lap(const float* __restrict__ src,
                                             const float* __restrict__ src2,
                                             float* __restrict__ dst,
                                             const int* __restrict__ idx,
                                             const float* __restrict__ w) {
    int n = blockIdx.x * 256 + threadIdx.x;
    if (n >= NPIXF) return;
    float a0 = 0.f, a1 = 0.f, a2 = 0.f, a3 = 0.f, a4 = 0.f, a5 = 0.f, a6 = 0.f, a7 = 0.f;
    const int* ip = idx + (size_t)n * NN;
    const float* wp = w + (size_t)n * NN;
#pragma unroll
    for (int j = 0; j < NN; ++j) {
        int nj = ip[j];
        float wj = wp[j];
        const float4* p = (const float4*)(src + (size_t)nj * 8);
        float4 x0 = p[0], x1 = p[1];
        a0 += wj * x0.x; a1 += wj * x0.y; a2 += wj * x0.z; a3 += wj * x0.w;
        a4 += wj * x1.x; a5 += wj * x1.y; a6 += wj * x1.z; a7 += wj * x1.w;
    }
    float4 o0, o1;
    if (FIRST) {
        o0 = make_float4(a0, a1, a2, a3);
        o1 = make_float4(a4, a5, a6, a7);
    } else {
        const float4* q = (const float4*)(src2 + (size_t)n * 8);
        float4 q0 = q[0], q1 = q[1];
        o0 = make_float4(2.f * a0 - q0.x, 2.f * a1 - q0.y, 2.f * a2 - q0.z, 2.f * a3 - q0.w);
        o1 = make_float4(2.f * a4 - q1.x, 2.f * a5 - q1.y, 2.f * a6 - q1.z, 2.f * a7 - q1.w);
    }
    float4* d = (float4*)(dst + (size_t)n * 8);
    d[0] = o0;
    d[1] = o1;
}

// ---------------------------------------------------------------------------
// fused epilogue, branches 1&2: out_k = sum_k T_k W_k + b -> relu -> LN -> pool4
// group = 32 lanes handles one (b, coarse node c); 8 groups / block.
__global__ __launch_bounds__(256) void k_epiA(
    const float* __restrict__ xt, const float* __restrict__ t1, const float* __restrict__ t2,
    const float* __restrict__ t3, const float* __restrict__ t4, const float* __restrict__ t5,
    const float* __restrict__ W1a, const float* __restrict__ b1a,
    const float* __restrict__ g1a, const float* __restrict__ be1a,
    const float* __restrict__ W2a, const float* __restrict__ b2a,
    const float* __restrict__ g2a, const float* __restrict__ be2a,
    float* __restrict__ h1p, float* __restrict__ h2p) {
    int f = threadIdx.x & 31;
    int grp = threadIdx.x >> 5;
    int g = blockIdx.x * 8 + grp;   // [0, 4*NCC)
    int c = g >> 2;
    int b = g & 3;

    float w1[8], w2[12];
#pragma unroll
    for (int k = 0; k < 8; ++k) w1[k] = W1a[k * 32 + f];
#pragma unroll
    for (int k = 0; k < 12; ++k) w2[k] = W2a[k * 32 + f];
    float bb1 = b1a[f], gg1 = g1a[f], bt1 = be1a[f];
    float bb2 = b2a[f], gg2 = g2a[f], bt2 = be2a[f];

    const float* tp0 = xt; const float* tp1 = t1; const float* tp2 = t2;
    const float* tp3 = t3; const float* tp4 = t4; const float* tp5 = t5;

    float acc1 = 0.f, acc2 = 0.f;
#pragma unroll
    for (int j = 0; j < 4; ++j) {
        int n = c * 4 + j;
        size_t off = (size_t)n * 8 + b * 2;
        float tv[12];
        {
            float2 v;
            v = *(const float2*)(tp0 + off); tv[0] = v.x; tv[1] = v.y;
            v = *(const float2*)(tp1 + off); tv[2] = v.x; tv[3] = v.y;
            v = *(const float2*)(tp2 + off); tv[4] = v.x; tv[5] = v.y;
            v = *(const float2*)(tp3 + off); tv[6] = v.x; tv[7] = v.y;
            v = *(const float2*)(tp4 + off); tv[8] = v.x; tv[9] = v.y;
            v = *(const float2*)(tp5 + off); tv[10] = v.x; tv[11] = v.y;
        }
        float o1 = bb1;
#pragma unroll
        for (int k = 0; k < 8; ++k) o1 += tv[k] * w1[k];
        o1 = fmaxf(o1, 0.f);
        float o2 = bb2;
#pragma unroll
        for (int k = 0; k < 12; ++k) o2 += tv[k] * w2[k];
        o2 = fmaxf(o2, 0.f);
        // LayerNorm over 32 features (lanes)
        float s1 = o1, q1 = o1 * o1, s2 = o2, q2 = o2 * o2;
#pragma unroll
        for (int m = 16; m >= 1; m >>= 1) {
            s1 += __shfl_xor(s1, m, 32);
            q1 += __shfl_xor(q1, m, 32);
            s2 += __shfl_xor(s2, m, 32);
            q2 += __shfl_xor(q2, m, 32);
        }
        float m1 = s1 * 0.03125f, v1 = q1 * 0.03125f - m1 * m1;
        float m2 = s2 * 0.03125f, v2 = q2 * 0.03125f - m2 * m2;
        acc1 += (o1 - m1) * rsqrtf(v1 + 1e-5f) * gg1 + bt1;
        acc2 += (o2 - m2) * rsqrtf(v2 + 1e-5f) * gg2 + bt2;
    }
    size_t oo = ((size_t)b * NCC + c) * 32 + f;
    h1p[oo] = acc1 * 0.25f;
    h2p[oo] = acc2 * 0.25f;
}

// fused epilogue branch 3 (64 features, K=8); group = 64 lanes per (b, c)
__global__ __launch_bounds__(256) void k_epiB(
    const float* __restrict__ xt, const float* __restrict__ t1, const float* __restrict__ t2,
    const float* __restrict__ t3, const float* __restrict__ t4, const float* __restrict__ t5,
    const float* __restrict__ t6, const float* __restrict__ t7,
    const float* __restrict__ W3a, const float* __restrict__ b3a,
    const float* __restrict__ g3a, const float* __restrict__ be3a,
    float* __restrict__ h3p) {
    int f = threadIdx.x & 63;
    int grp = threadIdx.x >> 6;
    int g = blockIdx.x * 4 + grp;
    int c = g >> 2;
    int b = g & 3;

    float w3[16];
#pragma unroll
    for (int k = 0; k < 16; ++k) w3[k] = W3a[k * 64 + f];
    float bb = b3a[f], gg = g3a[f], bt = be3a[f];

    const float* tp0 = xt; const float* tp1 = t1; const float* tp2 = t2; const float* tp3 = t3;
    const float* tp4 = t4; const float* tp5 = t5; const float* tp6 = t6; const float* tp7 = t7;

    float acc = 0.f;
#pragma unroll
    for (int j = 0; j < 4; ++j) {
        int n = c * 4 + j;
        size_t off = (size_t)n * 8 + b * 2;
        float tv[16];
        {
            float2 v;
            v = *(const float2*)(tp0 + off); tv[0] = v.x; tv[1] = v.y;
            v = *(const float2*)(tp1 + off); tv[2] = v.x; tv[3] = v.y;
            v = *(const float2*)(tp2 + off); tv[4] = v.x; tv[5] = v.y;
            v = *(const float2*)(tp3 + off); tv[6] = v.x; tv[7] = v.y;
            v = *(const float2*)(tp4 + off); tv[8] = v.x; tv[9] = v.y;
            v = *(const float2*)(tp5 + off); tv[10] = v.x; tv[11] = v.y;
            v = *(const float2*)(tp6 + off); tv[12] = v.x; tv[13] = v.y;
            v = *(const float2*)(tp7 + off); tv[14] = v.x; tv[15] = v.y;
        }
        float o = bb;
#pragma unroll
        for (int k = 0; k < 16; ++k) o += tv[k] * w3[k];
        o = fmaxf(o, 0.f);
        float s = o, q = o * o;
#pragma unroll
        for (int m = 32; m >= 1; m >>= 1) {
            s += __shfl_xor(s, m, 64);
            q += __shfl_xor(q, m, 64);
        }
        float mu = s * 0.015625f, va = q * 0.015625f - mu * mu;
        acc += (o - mu) * rsqrtf(va + 1e-5f) * gg + bt;
    }
    h3p[((size_t)b * NCC + c) * 64 + f] = acc * 0.25f;
}

// ---------------------------------------------------------------------------
// coarse-graph K=2 Chebyshev conv + relu + LN, writing into the concat output.
// out[b][c][f] = LN(relu(b + y0 @ Wb[0] + y1 @ Wb[1]))
// y0 = h[b][c][:], y1 = sum_j w[c,j] h[b][idx[c,j]][:]
template <int FD>
__global__ __launch_bounds__(256) void k_coarse(
    const float* __restrict__ h, const int* __restrict__ idx, const float* __restrict__ w,
    const float* __restrict__ Wb, const float* __restrict__ bv, const float* __restrict__ gv,
    const float* __restrict__ bev, float* __restrict__ out) {
    constexpr int GPB = 256 / FD;
    __shared__ float ylds[GPB][2 * FD];
    int lane = threadIdx.x & (FD - 1);
    int grp = threadIdx.x / FD;

    float w0r[FD], w1r[FD];
#pragma unroll
    for (int u = 0; u < FD; ++u) {
        w0r[u] = Wb[u * FD + lane];
        w1r[u] = Wb[FD * FD + u * FD + lane];
    }
    float bb = bv[lane], gg = gv[lane], bt = bev[lane];

    int ngrp = gridDim.x * GPB;
    for (int g = blockIdx.x * GPB + grp; g < 4 * NCC; g += ngrp) {
        int c = g >> 2;
        int b = g & 3;
        const float* hb = h + (size_t)b * NCC * FD;
        float y0 = hb[(size_t)c * FD + lane];
        float y1 = 0.f;
#pragma unroll
        for (int j = 0; j < 8; ++j) {
            int nj = idx[c * 8 + j];
            float wj = w[c * 8 + j];
            y1 += wj * hb[(size_t)nj * FD + lane];
        }
        ylds[grp][lane] = y0;
        ylds[grp][FD + lane] = y1;
        // group is contained in one wave -> wave-synchronous; compiler orders LDS ops
        float o = bb;
#pragma unroll
        for (int u = 0; u < FD; ++u) o += ylds[grp][u] * w0r[u];
#pragma unroll
        for (int u = 0; u < FD; ++u) o += ylds[grp][FD + u] * w1r[u];
        o = fmaxf(o, 0.f);
        float s = o, q = o * o;
#pragma unroll
        for (int m = FD / 2; m >= 1; m >>= 1) {
            s += __shfl_xor(s, m, FD);
            q += __shfl_xor(q, m, FD);
        }
        float mu = s * (1.f / FD), va = q * (1.f / FD) - mu * mu;
        float r = (o - mu) * rsqrtf(va + 1e-5f) * gg + bt;
        out[((size_t)b * NCC + c) * 128 + lane] = r;
    }
}

// ---------------------------------------------------------------------------
extern "C" void kernel_launch(void* const* d_in, const int* in_sizes, int n_in,
                              void* d_out, int out_size, void* d_ws, size_t ws_size,
                              hipStream_t stream) {
    const float* maps = (const float*)d_in[0];
    const float* w8   = (const float*)d_in[1];
    const float* w20  = (const float*)d_in[2];
    const float* w8s  = (const float*)d_in[3];
    const int*   idx8  = (const int*)d_in[4];
    const int*   idx20 = (const int*)d_in[5];
    const int*   idx8s = (const int*)d_in[6];
    const float* W1a = (const float*)d_in[7];
    const float* b1a = (const float*)d_in[8];
    const float* g1a = (const float*)d_in[9];
    const float* be1a = (const float*)d_in[10];
    const float* W1b = (const float*)d_in[11];
    const float* b1b = (const float*)d_in[12];
    const float* g1b = (const float*)d_in[13];
    const float* be1b = (const float*)d_in[14];
    const float* W2a = (const float*)d_in[15];
    const float* b2a = (const float*)d_in[16];
    const float* g2a = (const float*)d_in[17];
    const float* be2a = (const float*)d_in[18];
    const float* W2b = (const float*)d_in[19];
    const float* b2b = (const float*)d_in[20];
    const float* g2b = (const float*)d_in[21];
    const float* be2b = (const float*)d_in[22];
    const float* W3a = (const float*)d_in[23];
    const float* b3a = (const float*)d_in[24];
    const float* g3a = (const float*)d_in[25];
    const float* be3a = (const float*)d_in[26];
    const float* W3b = (const float*)d_in[27];
    const float* b3b = (const float*)d_in[28];
    const float* g3b = (const float*)d_in[29];
    const float* be3b = (const float*)d_in[30];
    float* out = (float*)d_out;

    // workspace layout (floats):
    //   xt       [0, 1572864)
    //   slot[i]  1572864*(1+i), i=0..6     (T buffers, reused between chains)
    //   h1p      12582912  (+6291456)
    //   h2p      18874368  (+6291456)
    //   h3p      25165824  (+12582912)  -> 37748736 floats = 151 MB
    float* ws = (float*)d_ws;
    float* xt = ws;
    float* slot[7];
    for (int i = 0; i < 7; ++i) slot[i] = ws + (size_t)1572864 * (1 + i);
    float* h1p = ws + (size_t)12582912;
    float* h2p = ws + (size_t)18874368;
    float* h3p = ws + (size_t)25165824;

    dim3 blk(256);
    dim3 gN(NPIXF / 256);  // 768

    k_transpose2<<<gN, blk, 0, stream>>>(maps, xt);

    // 8-neighbor chain: T1..T5 (branch1 uses T0..T3, branch2 T0..T5)
    k_lap<8, true><<<gN, blk, 0, stream>>>(xt, nullptr, slot[0], idx8, w8);
    k_lap<8, false><<<gN, blk, 0, stream>>>(slot[0], xt, slot[1], idx8, w8);
    k_lap<8, false><<<gN, blk, 0, stream>>>(slot[1], slot[0], slot[2], idx8, w8);
    k_lap<8, false><<<gN, blk, 0, stream>>>(slot[2], slot[1], slot[3], idx8, w8);
    k_lap<8, false><<<gN, blk, 0, stream>>>(slot[3], slot[2], slot[4], idx8, w8);

    k_epiA<<<24576, blk, 0, stream>>>(xt, slot[0], slot[1], slot[2], slot[3], slot[4],
                                      W1a, b1a, g1a, be1a, W2a, b2a, g2a, be2a, h1p, h2p);

    // 20-neighbor chain: T1..T7 (branch3, K=8) — reuses slots
    k_lap<20, true><<<gN, blk, 0, stream>>>(xt, nullptr, slot[0], idx20, w20);
    k_lap<20, false><<<gN, blk, 0, stream>>>(slot[0], xt, slot[1], idx20, w20);
    k_lap<20, false><<<gN, blk, 0, stream>>>(slot[1], slot[0], slot[2], idx20, w20);
    k_lap<20, false><<<gN, blk, 0, stream>>>(slot[2], slot[1], slot[3], idx20, w20);
    k_lap<20, false><<<gN, blk, 0, stream>>>(slot[3], slot[2], slot[4], idx20, w20);
    k_lap<20, false><<<gN, blk, 0, stream>>>(slot[4], slot[3], slot[5], idx20, w20);
    k_lap<20, false><<<gN, blk, 0, stream>>>(slot[5], slot[4], slot[6], idx20, w20);

    k_epiB<<<49152, blk, 0, stream>>>(xt, slot[0], slot[1], slot[2], slot[3], slot[4],
                                      slot[5], slot[6], W3a, b3a, g3a, be3a, h3p);

    // coarse graph convs -> concatenated output [B][NCC][128]
    k_coarse<32><<<2048, blk, 0, stream>>>(h1p, idx8s, w8s, W1b, b1b, g1b, be1b, out + 0);
    k_coarse<32><<<2048, blk, 0, stream>>>(h2p, idx8s, w8s, W2b, b2b, g2b, be2b, out + 32);
    k_coarse<64><<<2048, blk, 0, stream>>>(h3p, idx8s, w8s, W3b, b3b, g3b, be3b, out + 64);
}

// Round 4
// 906.446 us; speedup vs baseline: 1.4181x; 1.4181x over previous
//
#include <hip/hip_runtime.h>
#include <math.h>

#define NPIXF 196608   // fine nodes (12*128*128)
#define NCC   49152    // coarse nodes (NPIXF/4)
// T layout: [N][B*2] = 8 floats (32B) per node  (b major, ch minor)

// ---------------------------------------------------------------------------
// transpose idx/w [N][NN] -> [NN][N] so lap streams are coalesced
template <int NN>
__global__ __launch_bounds__(256) void k_tiw(const int* __restrict__ idx,
                                             const float* __restrict__ w,
                                             int* __restrict__ idxT,
                                             float* __restrict__ wT) {
    int n = blockIdx.x * 256 + threadIdx.x;
    if (n >= NPIXF) return;
#pragma unroll
    for (int j = 0; j < NN; ++j) {
        idxT[j * NPIXF + n] = idx[(size_t)n * NN + j];
        wT[j * NPIXF + n]   = w[(size_t)n * NN + j];
    }
}

// transpose maps [B][N][2] -> xt [N][B][2]
__global__ __launch_bounds__(256) void k_transpose2(const float* __restrict__ maps,
                                                    float* __restrict__ xt) {
    int n = blockIdx.x * 256 + threadIdx.x;
    if (n >= NPIXF) return;
    const float2* m2 = (const float2*)maps;
    float2 v0 = m2[0 * NPIXF + n];
    float2 v1 = m2[1 * NPIXF + n];
    float2 v2 = m2[2 * NPIXF + n];
    float2 v3 = m2[3 * NPIXF + n];
    float4* o = (float4*)(xt + (size_t)n * 8);
    o[0] = make_float4(v0.x, v0.y, v1.x, v1.y);
    o[1] = make_float4(v2.x, v2.y, v3.x, v3.y);
}

// ---------------------------------------------------------------------------
// one Chebyshev step; 2 threads per node (each owns a 16B half of the payload)
// FIRST: dst = lap(src); else dst = 2*lap(src) - src2
template <int NN, bool FIRST>
__global__ __launch_bounds__(256) void k_lap2(const float* __restrict__ src,
                                              const float* __restrict__ src2,
                                              float* __restrict__ dst,
                                              const int* __restrict__ idxT,
                                              const float* __restrict__ wT) {
    int t = blockIdx.x * 256 + threadIdx.x;
    int n = t >> 1;
    int h = (t & 1) * 4;
    if (n >= NPIXF) return;
    int nj[NN]; float wj[NN];
#pragma unroll
    for (int j = 0; j < NN; ++j) {
        nj[j] = idxT[j * NPIXF + n];
        wj[j] = wT[j * NPIXF + n];
    }
    float4 a = make_float4(0.f, 0.f, 0.f, 0.f);
#pragma unroll
    for (int j = 0; j < NN; ++j) {
        const float4 x = *(const float4*)(src + (size_t)nj[j] * 8 + h);
        a.x = fmaf(wj[j], x.x, a.x);
        a.y = fmaf(wj[j], x.y, a.y);
        a.z = fmaf(wj[j], x.z, a.z);
        a.w = fmaf(wj[j], x.w, a.w);
    }
    float4 o;
    if (FIRST) {
        o = a;
    } else {
        float4 qv = *(const float4*)(src2 + (size_t)n * 8 + h);
        o = make_float4(2.f * a.x - qv.x, 2.f * a.y - qv.y,
                        2.f * a.z - qv.z, 2.f * a.w - qv.w);
    }
    *(float4*)(dst + (size_t)n * 8 + h) = o;
}

// ---------------------------------------------------------------------------
// epilogue branches 1&2 (F=32): sum_k T_k W_k + b -> relu -> LN -> pool4
// two-phase, shuffle-free. Block=256 (4 waves), wave covers 16 fine nodes x 4 b.
__global__ __launch_bounds__(256) void k_epiA(
    const float* __restrict__ t0, const float* __restrict__ t1, const float* __restrict__ t2,
    const float* __restrict__ t3, const float* __restrict__ t4, const float* __restrict__ t5,
    const float* __restrict__ W1a, const float* __restrict__ b1a,
    const float* __restrict__ g1a, const float* __restrict__ be1a,
    const float* __restrict__ W2a, const float* __restrict__ b2a,
    const float* __restrict__ g2a, const float* __restrict__ be2a,
    float* __restrict__ h1p, float* __restrict__ h2p) {
    __shared__ float wcA[32 * 24];        // [f][0..7 w1 | 8..19 w2 | 20 b1 | 21 b2]
    __shared__ float tvlds[4 * 64 * 12];  // per wave: 64 cb rows of 12
    __shared__ float mrA[256 * 4];        // [cb][m1,r1,m2,r2]

    int tid = threadIdx.x;
    if (tid < 64) {               // W1a: 8x32
        int kk = tid >> 3, f4 = (tid & 7) * 4;
        float4 v = *(const float4*)(W1a + kk * 32 + f4);
        wcA[(f4 + 0) * 24 + kk] = v.x; wcA[(f4 + 1) * 24 + kk] = v.y;
        wcA[(f4 + 2) * 24 + kk] = v.z; wcA[(f4 + 3) * 24 + kk] = v.w;
    } else if (tid < 160) {       // W2a: 12x32
        int u = tid - 64;
        int kk = u >> 3, f4 = (u & 7) * 4;
        float4 v = *(const float4*)(W2a + kk * 32 + f4);
        wcA[(f4 + 0) * 24 + 8 + kk] = v.x; wcA[(f4 + 1) * 24 + 8 + kk] = v.y;
        wcA[(f4 + 2) * 24 + 8 + kk] = v.z; wcA[(f4 + 3) * 24 + 8 + kk] = v.w;
    } else if (tid < 192) {
        wcA[(tid - 160) * 24 + 20] = b1a[tid - 160];
    } else if (tid < 224) {
        wcA[(tid - 192) * 24 + 21] = b2a[tid - 192];
    }
    __syncthreads();

    int lane = tid & 63;
    int wv = tid >> 6;
    int b = lane & 3;
    int n = blockIdx.x * 64 + wv * 16 + (lane >> 2);

    // phase 1: coalesced tv loads, f-loop for mean/var (no shuffles)
    float tv[12];
    {
        const float* tp[6] = {t0, t1, t2, t3, t4, t5};
#pragma unroll
        for (int t = 0; t < 6; ++t) {
            float2 v = *(const float2*)(tp[t] + (size_t)n * 8 + b * 2);
            tv[2 * t] = v.x; tv[2 * t + 1] = v.y;
        }
    }
    float* tvw = tvlds + wv * (64 * 12);
    {
        float4* d4 = (float4*)(tvw + lane * 12);
        d4[0] = make_float4(tv[0], tv[1], tv[2], tv[3]);
        d4[1] = make_float4(tv[4], tv[5], tv[6], tv[7]);
        d4[2] = make_float4(tv[8], tv[9], tv[10], tv[11]);
    }
    float s1 = 0.f, q1 = 0.f, s2 = 0.f, q2 = 0.f;
#pragma unroll 4
    for (int f = 0; f < 32; ++f) {
        const float* wc = wcA + f * 24;
        const float4 u0 = *(const float4*)(wc + 0), u1 = *(const float4*)(wc + 4);
        const float4 v0 = *(const float4*)(wc + 8), v1 = *(const float4*)(wc + 12),
                     v2 = *(const float4*)(wc + 16);
        float o1 = wc[20];
        o1 = fmaf(tv[0], u0.x, o1); o1 = fmaf(tv[1], u0.y, o1);
        o1 = fmaf(tv[2], u0.z, o1); o1 = fmaf(tv[3], u0.w, o1);
        o1 = fmaf(tv[4], u1.x, o1); o1 = fmaf(tv[5], u1.y, o1);
        o1 = fmaf(tv[6], u1.z, o1); o1 = fmaf(tv[7], u1.w, o1);
        o1 = fmaxf(o1, 0.f);
        float o2 = wc[21];
        o2 = fmaf(tv[0], v0.x, o2); o2 = fmaf(tv[1], v0.y, o2);
        o2 = fmaf(tv[2], v0.z, o2); o2 = fmaf(tv[3], v0.w, o2);
        o2 = fmaf(tv[4], v1.x, o2); o2 = fmaf(tv[5], v1.y, o2);
        o2 = fmaf(tv[6], v1.z, o2); o2 = fmaf(tv[7], v1.w, o2);
        o2 = fmaf(tv[8], v2.x, o2); o2 = fmaf(tv[9], v2.y, o2);
        o2 = fmaf(tv[10], v2.z, o2); o2 = fmaf(tv[11], v2.w, o2);
        o2 = fmaxf(o2, 0.f);
        s1 += o1; q1 = fmaf(o1, o1, q1);
        s2 += o2; q2 = fmaf(o2, o2, q2);
    }
    {
        float m1 = s1 * 0.03125f, va1 = q1 * 0.03125f - m1 * m1;
        float m2 = s2 * 0.03125f, va2 = q2 * 0.03125f - m2 * m2;
        *(float4*)(mrA + (wv * 64 + lane) * 4) =
            make_float4(m1, rsqrtf(va1 + 1e-5f), m2, rsqrtf(va2 + 1e-5f));
    }
    // wave-local LDS: same wave wrote what it reads; compiler orders DS ops.

    // phase 2: lanes 0..31 -> branch1 feature f, lanes 32..63 -> branch2
    int f = lane & 31;
    int br = lane >> 5;
    float wreg[12];
#pragma unroll
    for (int k = 0; k < 12; ++k) {
        float w1v = (k < 8) ? W1a[k * 32 + f] : 0.f;
        wreg[k] = br ? W2a[k * 32 + f] : w1v;
    }
    float bb = br ? b2a[f] : b1a[f];
    float gg = br ? g2a[f] : g1a[f];
    float bt = br ? be2a[f] : be1a[f];
    float* outp = br ? h2p : h1p;
    int C0 = blockIdx.x * 16 + wv * 4;
#pragma unroll
    for (int cl = 0; cl < 4; ++cl) {
#pragma unroll
        for (int b2 = 0; b2 < 4; ++b2) {
            float acc = 0.f;
#pragma unroll
            for (int j = 0; j < 4; ++j) {
                int cb = (cl * 4 + j) * 4 + b2;
                const float* tp = tvw + cb * 12;
                const float4 a0 = *(const float4*)(tp + 0);
                const float4 a1 = *(const float4*)(tp + 4);
                const float4 a2 = *(const float4*)(tp + 8);
                float o = bb;
                o = fmaf(a0.x, wreg[0], o); o = fmaf(a0.y, wreg[1], o);
                o = fmaf(a0.z, wreg[2], o); o = fmaf(a0.w, wreg[3], o);
                o = fmaf(a1.x, wreg[4], o); o = fmaf(a1.y, wreg[5], o);
                o = fmaf(a1.z, wreg[6], o); o = fmaf(a1.w, wreg[7], o);
                o = fmaf(a2.x, wreg[8], o); o = fmaf(a2.y, wreg[9], o);
                o = fmaf(a2.z, wreg[10], o); o = fmaf(a2.w, wreg[11], o);
                o = fmaxf(o, 0.f);
                const float4 mr4 = *(const float4*)(mrA + (wv * 64 + cb) * 4);
                float m = br ? mr4.z : mr4.x;
                float r = br ? mr4.w : mr4.y;
                float v = (o - m) * r;
                acc += fmaf(v, gg, bt);
            }
            outp[((size_t)b2 * NCC + C0 + cl) * 32 + f] = acc * 0.25f;
        }
    }
}

// ---------------------------------------------------------------------------
// epilogue branch 3 (F=64, 8 T buffers) — same two-phase structure
__global__ __launch_bounds__(256) void k_epiB(
    const float* __restrict__ t0, const float* __restrict__ t1, const float* __restrict__ t2,
    const float* __restrict__ t3, const float* __restrict__ t4, const float* __restrict__ t5,
    const float* __restrict__ t6, const float* __restrict__ t7,
    const float* __restrict__ W3a, const float* __restrict__ b3a,
    const float* __restrict__ g3a, const float* __restrict__ be3a,
    float* __restrict__ h3p) {
    __shared__ float wcol[64 * 20];       // [f][16 w | bias at 16] pad 20
    __shared__ float tvlds[4 * 64 * 20];  // per wave: 64 cb rows of 20 (16 used)
    __shared__ float mr[256 * 2];

    int tid = threadIdx.x;
    {
        int kk = tid >> 4, f4 = (tid & 15) * 4;
        float4 v = *(const float4*)(W3a + kk * 64 + f4);
        wcol[(f4 + 0) * 20 + kk] = v.x; wcol[(f4 + 1) * 20 + kk] = v.y;
        wcol[(f4 + 2) * 20 + kk] = v.z; wcol[(f4 + 3) * 20 + kk] = v.w;
        if (tid < 64) wcol[tid * 20 + 16] = b3a[tid];
    }
    __syncthreads();

    int lane = tid & 63;
    int wv = tid >> 6;
    int b = lane & 3;
    int n = blockIdx.x * 64 + wv * 16 + (lane >> 2);

    float tv[16];
    {
        const float* tp[8] = {t0, t1, t2, t3, t4, t5, t6, t7};
#pragma unroll
        for (int t = 0; t < 8; ++t) {
            float2 v = *(const float2*)(tp[t] + (size_t)n * 8 + b * 2);
            tv[2 * t] = v.x; tv[2 * t + 1] = v.y;
        }
    }
    float* tvw = tvlds + wv * (64 * 20);
    {
        float4* d4 = (float4*)(tvw + lane * 20);
        d4[0] = make_float4(tv[0], tv[1], tv[2], tv[3]);
        d4[1] = make_float4(tv[4], tv[5], tv[6], tv[7]);
        d4[2] = make_float4(tv[8], tv[9], tv[10], tv[11]);
        d4[3] = make_float4(tv[12], tv[13], tv[14], tv[15]);
    }
    float s = 0.f, q = 0.f;
#pragma unroll 4
    for (int f = 0; f < 64; ++f) {
        const float* wc = wcol + f * 20;
        const float4 w0 = *(const float4*)(wc + 0), w1 = *(const float4*)(wc + 4);
        const float4 w2 = *(const float4*)(wc + 8), w3 = *(const float4*)(wc + 12);
        float o = wc[16];
        o = fmaf(tv[0], w0.x, o);  o = fmaf(tv[1], w0.y, o);
        o = fmaf(tv[2], w0.z, o);  o = fmaf(tv[3], w0.w, o);
        o = fmaf(tv[4], w1.x, o);  o = fmaf(tv[5], w1.y, o);
        o = fmaf(tv[6], w1.z, o);  o = fmaf(tv[7], w1.w, o);
        o = fmaf(tv[8], w2.x, o);  o = fmaf(tv[9], w2.y, o);
        o = fmaf(tv[10], w2.z, o); o = fmaf(tv[11], w2.w, o);
        o = fmaf(tv[12], w3.x, o); o = fmaf(tv[13], w3.y, o);
        o = fmaf(tv[14], w3.z, o); o = fmaf(tv[15], w3.w, o);
        o = fmaxf(o, 0.f);
        s += o; q = fmaf(o, o, q);
    }
    {
        float m = s * 0.015625f;
        float va = q * 0.015625f - m * m;
        *(float2*)(mr + (wv * 64 + lane) * 2) = make_float2(m, rsqrtf(va + 1e-5f));
    }

    // phase 2: lane = f
    float wreg[16];
#pragma unroll
    for (int k = 0; k < 16; ++k) wreg[k] = W3a[k * 64 + lane];
    float bb = b3a[lane], gg = g3a[lane], bt = be3a[lane];
    int C0 = blockIdx.x * 16 + wv * 4;
#pragma unroll
    for (int cl = 0; cl < 4; ++cl) {
#pragma unroll
        for (int b2 = 0; b2 < 4; ++b2) {
            float acc = 0.f;
#pragma unroll
            for (int j = 0; j < 4; ++j) {
                int cb = (cl * 4 + j) * 4 + b2;
                const float* tp = tvw + cb * 20;
                const float4 a0 = *(const float4*)(tp + 0);
                const float4 a1 = *(const float4*)(tp + 4);
                const float4 a2 = *(const float4*)(tp + 8);
                const float4 a3 = *(const float4*)(tp + 12);
                float o = bb;
                o = fmaf(a0.x, wreg[0], o);  o = fmaf(a0.y, wreg[1], o);
                o = fmaf(a0.z, wreg[2], o);  o = fmaf(a0.w, wreg[3], o);
                o = fmaf(a1.x, wreg[4], o);  o = fmaf(a1.y, wreg[5], o);
                o = fmaf(a1.z, wreg[6], o);  o = fmaf(a1.w, wreg[7], o);
                o = fmaf(a2.x, wreg[8], o);  o = fmaf(a2.y, wreg[9], o);
                o = fmaf(a2.z, wreg[10], o); o = fmaf(a2.w, wreg[11], o);
                o = fmaf(a3.x, wreg[12], o); o = fmaf(a3.y, wreg[13], o);
                o = fmaf(a3.z, wreg[14], o); o = fmaf(a3.w, wreg[15], o);
                o = fmaxf(o, 0.f);
                const float2 mrv = *(const float2*)(mr + (wv * 64 + cb) * 2);
                float v = (o - mrv.x) * mrv.y;
                acc += fmaf(v, gg, bt);
            }
            h3p[((size_t)b2 * NCC + C0 + cl) * 64 + lane] = acc * 0.25f;
        }
    }
}

// ---------------------------------------------------------------------------
// coarse-graph K=2 conv + relu + LN -> concat output (b128 LDS broadcast reads)
template <int FD>
__global__ __launch_bounds__(256) void k_coarse(
    const float* __restrict__ h, const int* __restrict__ idx, const float* __restrict__ w,
    const float* __restrict__ Wb, const float* __restrict__ bv, const float* __restrict__ gv,
    const float* __restrict__ bev, float* __restrict__ out) {
    constexpr int GPB = 256 / FD;
    __shared__ float ylds[GPB][2 * FD];
    int lane = threadIdx.x & (FD - 1);
    int grp = threadIdx.x / FD;

    float w0r[FD], w1r[FD];
#pragma unroll
    for (int u = 0; u < FD; ++u) {
        w0r[u] = Wb[u * FD + lane];
        w1r[u] = Wb[FD * FD + u * FD + lane];
    }
    float bb = bv[lane], gg = gv[lane], bt = bev[lane];

    int ngrp = gridDim.x * GPB;
    for (int g = blockIdx.x * GPB + grp; g < 4 * NCC; g += ngrp) {
        int c = g >> 2;
        int b = g & 3;
        const float* hb = h + (size_t)b * NCC * FD;
        float y0 = hb[(size_t)c * FD + lane];
        float y1 = 0.f;
#pragma unroll
        for (int j = 0; j < 8; ++j) {
            int nj = idx[c * 8 + j];
            float wj = w[c * 8 + j];
            y1 = fmaf(wj, hb[(size_t)nj * FD + lane], y1);
        }
        ylds[grp][lane] = y0;
        ylds[grp][FD + lane] = y1;
        const float4* y4 = (const float4*)(&ylds[grp][0]);
        float o = bb;
#pragma unroll
        for (int u = 0; u < FD / 4; ++u) {
            float4 yv = y4[u];
            o = fmaf(yv.x, w0r[4 * u + 0], o);
            o = fmaf(yv.y, w0r[4 * u + 1], o);
            o = fmaf(yv.z, w0r[4 * u + 2], o);
            o = fmaf(yv.w, w0r[4 * u + 3], o);
        }
#pragma unroll
        for (int u = 0; u < FD / 4; ++u) {
            float4 yv = y4[FD / 4 + u];
            o = fmaf(yv.x, w1r[4 * u + 0], o);
            o = fmaf(yv.y, w1r[4 * u + 1], o);
            o = fmaf(yv.z, w1r[4 * u + 2], o);
            o = fmaf(yv.w, w1r[4 * u + 3], o);
        }
        o = fmaxf(o, 0.f);
        float s = o, q = o * o;
#pragma unroll
        for (int m = FD / 2; m >= 1; m >>= 1) {
            s += __shfl_xor(s, m, FD);
            q += __shfl_xor(q, m, FD);
        }
        float mu = s * (1.f / FD), va = q * (1.f / FD) - mu * mu;
        float r = (o - mu) * rsqrtf(va + 1e-5f) * gg + bt;
        out[((size_t)b * NCC + c) * 128 + lane] = r;
    }
}

// ---------------------------------------------------------------------------
extern "C" void kernel_launch(void* const* d_in, const int* in_sizes, int n_in,
                              void* d_out, int out_size, void* d_ws, size_t ws_size,
                              hipStream_t stream) {
    const float* maps = (const float*)d_in[0];
    const float* w8   = (const float*)d_in[1];
    const float* w20  = (const float*)d_in[2];
    const float* w8s  = (const float*)d_in[3];
    const int*   idx8  = (const int*)d_in[4];
    const int*   idx20 = (const int*)d_in[5];
    const int*   idx8s = (const int*)d_in[6];
    const float* W1a = (const float*)d_in[7];
    const float* b1a = (const float*)d_in[8];
    const float* g1a = (const float*)d_in[9];
    const float* be1a = (const float*)d_in[10];
    const float* W1b = (const float*)d_in[11];
    const float* b1b = (const float*)d_in[12];
    const float* g1b = (const float*)d_in[13];
    const float* be1b = (const float*)d_in[14];
    const float* W2a = (const float*)d_in[15];
    const float* b2a = (const float*)d_in[16];
    const float* g2a = (const float*)d_in[17];
    const float* be2a = (const float*)d_in[18];
    const float* W2b = (const float*)d_in[19];
    const float* b2b = (const float*)d_in[20];
    const float* g2b = (const float*)d_in[21];
    const float* be2b = (const float*)d_in[22];
    const float* W3a = (const float*)d_in[23];
    const float* b3a = (const float*)d_in[24];
    const float* g3a = (const float*)d_in[25];
    const float* be3a = (const float*)d_in[26];
    const float* W3b = (const float*)d_in[27];
    const float* b3b = (const float*)d_in[28];
    const float* g3b = (const float*)d_in[29];
    const float* be3b = (const float*)d_in[30];
    float* out = (float*)d_out;

    // workspace layout (floats), 151 MB total:
    //   xt       [0, 1572864)
    //   slot[i]  1572864*(1+i), i=0..6
    //   h1p      12582912 (+6291456)   [idx8T/w8T overlay: dead before epiA]
    //   h2p      18874368 (+6291456)
    //   h3p      25165824 (+12582912)  [idx20T/w20T overlay: dead before epiB]
    float* ws = (float*)d_ws;
    float* xt = ws;
    float* slot[7];
    for (int i = 0; i < 7; ++i) slot[i] = ws + (size_t)1572864 * (1 + i);
    float* h1p = ws + (size_t)12582912;
    float* h2p = ws + (size_t)18874368;
    float* h3p = ws + (size_t)25165824;
    int*   idx8T  = (int*)(ws + 12582912);
    float* w8T    = ws + 12582912 + 1572864;
    int*   idx20T = (int*)(ws + 25165824);
    float* w20T   = ws + 25165824 + 3932160;

    dim3 blk(256);
    dim3 gN(NPIXF / 256);        // 768
    dim3 gL(2 * NPIXF / 256);    // 1536 (2 threads/node)
    dim3 gE(NPIXF / 64);         // 3072 (epilogues: 64 fine nodes/block)

    k_tiw<8><<<gN, blk, 0, stream>>>(idx8, w8, idx8T, w8T);
    k_tiw<20><<<gN, blk, 0, stream>>>(idx20, w20, idx20T, w20T);
    k_transpose2<<<gN, blk, 0, stream>>>(maps, xt);

    // 8-neighbor chain: T1..T5
    k_lap2<8, true><<<gL, blk, 0, stream>>>(xt, nullptr, slot[0], idx8T, w8T);
    k_lap2<8, false><<<gL, blk, 0, stream>>>(slot[0], xt, slot[1], idx8T, w8T);
    k_lap2<8, false><<<gL, blk, 0, stream>>>(slot[1], slot[0], slot[2], idx8T, w8T);
    k_lap2<8, false><<<gL, blk, 0, stream>>>(slot[2], slot[1], slot[3], idx8T, w8T);
    k_lap2<8, false><<<gL, blk, 0, stream>>>(slot[3], slot[2], slot[4], idx8T, w8T);

    k_epiA<<<gE, blk, 0, stream>>>(xt, slot[0], slot[1], slot[2], slot[3], slot[4],
                                   W1a, b1a, g1a, be1a, W2a, b2a, g2a, be2a, h1p, h2p);

    // 20-neighbor chain: T1..T7
    k_lap2<20, true><<<gL, blk, 0, stream>>>(xt, nullptr, slot[0], idx20T, w20T);
    k_lap2<20, false><<<gL, blk, 0, stream>>>(slot[0], xt, slot[1], idx20T, w20T);
    k_lap2<20, false><<<gL, blk, 0, stream>>>(slot[1], slot[0], slot[2], idx20T, w20T);
    k_lap2<20, false><<<gL, blk, 0, stream>>>(slot[2], slot[1], slot[3], idx20T, w20T);
    k_lap2<20, false><<<gL, blk, 0, stream>>>(slot[3], slot[2], slot[4], idx20T, w20T);
    k_lap2<20, false><<<gL, blk, 0, stream>>>(slot[4], slot[3], slot[5], idx20T, w20T);
    k_lap2<20, false><<<gL, blk, 0, stream>>>(slot[5], slot[4], slot[6], idx20T, w20T);

    k_epiB<<<gE, blk, 0, stream>>>(xt, slot[0], slot[1], slot[2], slot[3], slot[4],
                                   slot[5], slot[6], W3a, b3a, g3a, be3a, h3p);

    // coarse graph convs -> concatenated output [B][NCC][128]
    k_coarse<32><<<2048, blk, 0, stream>>>(h1p, idx8s, w8s, W1b, b1b, g1b, be1b, out + 0);
    k_coarse<32><<<2048, blk, 0, stream>>>(h2p, idx8s, w8s, W2b, b2b, g2b, be2b, out + 32);
    k_coarse<64><<<2048, blk, 0, stream>>>(h3p, idx8s, w8s, W3b, b3b, g3b, be3b, out + 64);
}

// Round 5
// 890.698 us; speedup vs baseline: 1.4432x; 1.0177x over previous
//
#include <hip/hip_runtime.h>
#include <math.h>

#define NPIXF 196608   // fine nodes (12*128*128)
#define NCC   49152    // coarse nodes (NPIXF/4)
// T layout: [N][B*2] = 8 floats (32B) per node  (b major, ch minor)

typedef unsigned short bfu;

__device__ inline bfu f2bf(float x) {
    union { float f; unsigned u; } v; v.f = x;
    unsigned r = v.u + 0x7fff + ((v.u >> 16) & 1);   // RNE
    return (bfu)(r >> 16);
}
__device__ inline float bf2f(bfu b) {
    union { unsigned u; float f; } v; v.u = ((unsigned)b) << 16;
    return v.f;
}

// ---------------------------------------------------------------------------
// transpose idx/w [N][NN] -> [NN][N] so lap streams are coalesced
template <int NN>
__global__ __launch_bounds__(256) void k_tiw(const int* __restrict__ idx,
                                             const float* __restrict__ w,
                                             int* __restrict__ idxT,
                                             float* __restrict__ wT) {
    int n = blockIdx.x * 256 + threadIdx.x;
    if (n >= NPIXF) return;
#pragma unroll
    for (int j = 0; j < NN; ++j) {
        idxT[j * NPIXF + n] = idx[(size_t)n * NN + j];
        wT[j * NPIXF + n]   = w[(size_t)n * NN + j];
    }
}

// transpose maps [B][N][2] -> xt [N][B][2]
__global__ __launch_bounds__(256) void k_transpose2(const float* __restrict__ maps,
                                                    float* __restrict__ xt) {
    int n = blockIdx.x * 256 + threadIdx.x;
    if (n >= NPIXF) return;
    const float2* m2 = (const float2*)maps;
    float2 v0 = m2[0 * NPIXF + n];
    float2 v1 = m2[1 * NPIXF + n];
    float2 v2 = m2[2 * NPIXF + n];
    float2 v3 = m2[3 * NPIXF + n];
    float4* o = (float4*)(xt + (size_t)n * 8);
    o[0] = make_float4(v0.x, v0.y, v1.x, v1.y);
    o[1] = make_float4(v2.x, v2.y, v3.x, v3.y);
}

// ---------------------------------------------------------------------------
// one Chebyshev step; 2 threads per node (each owns a 16B half of the payload)
template <int NN, bool FIRST>
__global__ __launch_bounds__(256) void k_lap2(const float* __restrict__ src,
                                              const float* __restrict__ src2,
                                              float* __restrict__ dst,
                                              const int* __restrict__ idxT,
                                              const float* __restrict__ wT) {
    int t = blockIdx.x * 256 + threadIdx.x;
    int n = t >> 1;
    int h = (t & 1) * 4;
    if (n >= NPIXF) return;
    int nj[NN]; float wj[NN];
#pragma unroll
    for (int j = 0; j < NN; ++j) {
        nj[j] = idxT[j * NPIXF + n];
        wj[j] = wT[j * NPIXF + n];
    }
    float4 a = make_float4(0.f, 0.f, 0.f, 0.f);
#pragma unroll
    for (int j = 0; j < NN; ++j) {
        const float4 x = *(const float4*)(src + (size_t)nj[j] * 8 + h);
        a.x = fmaf(wj[j], x.x, a.x);
        a.y = fmaf(wj[j], x.y, a.y);
        a.z = fmaf(wj[j], x.z, a.z);
        a.w = fmaf(wj[j], x.w, a.w);
    }
    float4 o;
    if (FIRST) {
        o = a;
    } else {
        float4 qv = *(const float4*)(src2 + (size_t)n * 8 + h);
        o = make_float4(2.f * a.x - qv.x, 2.f * a.y - qv.y,
                        2.f * a.z - qv.z, 2.f * a.w - qv.w);
    }
    *(float4*)(dst + (size_t)n * 8 + h) = o;
}

// ---------------------------------------------------------------------------
// epilogue branches 1&2 (F=32): sum_k T_k W_k + b -> relu -> LN -> pool4
// two-phase, shuffle-free; writes bf16 h.
__global__ __launch_bounds__(256) void k_epiA(
    const float* __restrict__ t0, const float* __restrict__ t1, const float* __restrict__ t2,
    const float* __restrict__ t3, const float* __restrict__ t4, const float* __restrict__ t5,
    const float* __restrict__ W1a, const float* __restrict__ b1a,
    const float* __restrict__ g1a, const float* __restrict__ be1a,
    const float* __restrict__ W2a, const float* __restrict__ b2a,
    const float* __restrict__ g2a, const float* __restrict__ be2a,
    bfu* __restrict__ h1p, bfu* __restrict__ h2p) {
    __shared__ float wcA[32 * 24];        // [f][0..7 w1 | 8..19 w2 | 20 b1 | 21 b2]
    __shared__ float tvlds[4 * 64 * 12];  // per wave: 64 cb rows of 12
    __shared__ float mrA[256 * 4];        // [cb][m1,r1,m2,r2]

    int tid = threadIdx.x;
    if (tid < 64) {               // W1a: 8x32
        int kk = tid >> 3, f4 = (tid & 7) * 4;
        float4 v = *(const float4*)(W1a + kk * 32 + f4);
        wcA[(f4 + 0) * 24 + kk] = v.x; wcA[(f4 + 1) * 24 + kk] = v.y;
        wcA[(f4 + 2) * 24 + kk] = v.z; wcA[(f4 + 3) * 24 + kk] = v.w;
    } else if (tid < 160) {       // W2a: 12x32
        int u = tid - 64;
        int kk = u >> 3, f4 = (u & 7) * 4;
        float4 v = *(const float4*)(W2a + kk * 32 + f4);
        wcA[(f4 + 0) * 24 + 8 + kk] = v.x; wcA[(f4 + 1) * 24 + 8 + kk] = v.y;
        wcA[(f4 + 2) * 24 + 8 + kk] = v.z; wcA[(f4 + 3) * 24 + 8 + kk] = v.w;
    } else if (tid < 192) {
        wcA[(tid - 160) * 24 + 20] = b1a[tid - 160];
    } else if (tid < 224) {
        wcA[(tid - 192) * 24 + 21] = b2a[tid - 192];
    }
    __syncthreads();

    int lane = tid & 63;
    int wv = tid >> 6;
    int b = lane & 3;
    int n = blockIdx.x * 64 + wv * 16 + (lane >> 2);

    float tv[12];
    {
        const float* tp[6] = {t0, t1, t2, t3, t4, t5};
#pragma unroll
        for (int t = 0; t < 6; ++t) {
            float2 v = *(const float2*)(tp[t] + (size_t)n * 8 + b * 2);
            tv[2 * t] = v.x; tv[2 * t + 1] = v.y;
        }
    }
    float* tvw = tvlds + wv * (64 * 12);
    {
        float4* d4 = (float4*)(tvw + lane * 12);
        d4[0] = make_float4(tv[0], tv[1], tv[2], tv[3]);
        d4[1] = make_float4(tv[4], tv[5], tv[6], tv[7]);
        d4[2] = make_float4(tv[8], tv[9], tv[10], tv[11]);
    }
    float s1 = 0.f, q1 = 0.f, s2 = 0.f, q2 = 0.f;
#pragma unroll 4
    for (int f = 0; f < 32; ++f) {
        const float* wc = wcA + f * 24;
        const float4 u0 = *(const float4*)(wc + 0), u1 = *(const float4*)(wc + 4);
        const float4 v0 = *(const float4*)(wc + 8), v1 = *(const float4*)(wc + 12),
                     v2 = *(const float4*)(wc + 16);
        float o1 = wc[20];
        o1 = fmaf(tv[0], u0.x, o1); o1 = fmaf(tv[1], u0.y, o1);
        o1 = fmaf(tv[2], u0.z, o1); o1 = fmaf(tv[3], u0.w, o1);
        o1 = fmaf(tv[4], u1.x, o1); o1 = fmaf(tv[5], u1.y, o1);
        o1 = fmaf(tv[6], u1.z, o1); o1 = fmaf(tv[7], u1.w, o1);
        o1 = fmaxf(o1, 0.f);
        float o2 = wc[21];
        o2 = fmaf(tv[0], v0.x, o2); o2 = fmaf(tv[1], v0.y, o2);
        o2 = fmaf(tv[2], v0.z, o2); o2 = fmaf(tv[3], v0.w, o2);
        o2 = fmaf(tv[4], v1.x, o2); o2 = fmaf(tv[5], v1.y, o2);
        o2 = fmaf(tv[6], v1.z, o2); o2 = fmaf(tv[7], v1.w, o2);
        o2 = fmaf(tv[8], v2.x, o2); o2 = fmaf(tv[9], v2.y, o2);
        o2 = fmaf(tv[10], v2.z, o2); o2 = fmaf(tv[11], v2.w, o2);
        o2 = fmaxf(o2, 0.f);
        s1 += o1; q1 = fmaf(o1, o1, q1);
        s2 += o2; q2 = fmaf(o2, o2, q2);
    }
    {
        float m1 = s1 * 0.03125f, va1 = q1 * 0.03125f - m1 * m1;
        float m2 = s2 * 0.03125f, va2 = q2 * 0.03125f - m2 * m2;
        *(float4*)(mrA + (wv * 64 + lane) * 4) =
            make_float4(m1, rsqrtf(va1 + 1e-5f), m2, rsqrtf(va2 + 1e-5f));
    }
    // wave-local LDS: same wave wrote what it reads.

    int f = lane & 31;
    int br = lane >> 5;
    float wreg[12];
#pragma unroll
    for (int k = 0; k < 12; ++k) {
        float w1v = (k < 8) ? W1a[k * 32 + f] : 0.f;
        wreg[k] = br ? W2a[k * 32 + f] : w1v;
    }
    float bb = br ? b2a[f] : b1a[f];
    float gg = br ? g2a[f] : g1a[f];
    float bt = br ? be2a[f] : be1a[f];
    bfu* outp = br ? h2p : h1p;
    int C0 = blockIdx.x * 16 + wv * 4;
#pragma unroll
    for (int cl = 0; cl < 4; ++cl) {
#pragma unroll
        for (int b2 = 0; b2 < 4; ++b2) {
            float acc = 0.f;
#pragma unroll
            for (int j = 0; j < 4; ++j) {
                int cb = (cl * 4 + j) * 4 + b2;
                const float* tp = tvw + cb * 12;
                const float4 a0 = *(const float4*)(tp + 0);
                const float4 a1 = *(const float4*)(tp + 4);
                const float4 a2 = *(const float4*)(tp + 8);
                float o = bb;
                o = fmaf(a0.x, wreg[0], o); o = fmaf(a0.y, wreg[1], o);
                o = fmaf(a0.z, wreg[2], o); o = fmaf(a0.w, wreg[3], o);
                o = fmaf(a1.x, wreg[4], o); o = fmaf(a1.y, wreg[5], o);
                o = fmaf(a1.z, wreg[6], o); o = fmaf(a1.w, wreg[7], o);
                o = fmaf(a2.x, wreg[8], o); o = fmaf(a2.y, wreg[9], o);
                o = fmaf(a2.z, wreg[10], o); o = fmaf(a2.w, wreg[11], o);
                o = fmaxf(o, 0.f);
                const float4 mr4 = *(const float4*)(mrA + (wv * 64 + cb) * 4);
                float m = br ? mr4.z : mr4.x;
                float r = br ? mr4.w : mr4.y;
                float v = (o - m) * r;
                acc += fmaf(v, gg, bt);
            }
            outp[((size_t)b2 * NCC + C0 + cl) * 32 + f] = f2bf(acc * 0.25f);
        }
    }
}

// ---------------------------------------------------------------------------
// epilogue branch 3 (F=64, 8 T buffers) — same two-phase structure, bf16 h out
__global__ __launch_bounds__(256) void k_epiB(
    const float* __restrict__ t0, const float* __restrict__ t1, const float* __restrict__ t2,
    const float* __restrict__ t3, const float* __restrict__ t4, const float* __restrict__ t5,
    const float* __restrict__ t6, const float* __restrict__ t7,
    const float* __restrict__ W3a, const float* __restrict__ b3a,
    const float* __restrict__ g3a, const float* __restrict__ be3a,
    bfu* __restrict__ h3p) {
    __shared__ float wcol[64 * 20];       // [f][16 w | bias at 16] pad 20
    __shared__ float tvlds[4 * 64 * 20];
    __shared__ float mr[256 * 2];

    int tid = threadIdx.x;
    {
        int kk = tid >> 4, f4 = (tid & 15) * 4;
        float4 v = *(const float4*)(W3a + kk * 64 + f4);
        wcol[(f4 + 0) * 20 + kk] = v.x; wcol[(f4 + 1) * 20 + kk] = v.y;
        wcol[(f4 + 2) * 20 + kk] = v.z; wcol[(f4 + 3) * 20 + kk] = v.w;
        if (tid < 64) wcol[tid * 20 + 16] = b3a[tid];
    }
    __syncthreads();

    int lane = tid & 63;
    int wv = tid >> 6;
    int b = lane & 3;
    int n = blockIdx.x * 64 + wv * 16 + (lane >> 2);

    float tv[16];
    {
        const float* tp[8] = {t0, t1, t2, t3, t4, t5, t6, t7};
#pragma unroll
        for (int t = 0; t < 8; ++t) {
            float2 v = *(const float2*)(tp[t] + (size_t)n * 8 + b * 2);
            tv[2 * t] = v.x; tv[2 * t + 1] = v.y;
        }
    }
    float* tvw = tvlds + wv * (64 * 20);
    {
        float4* d4 = (float4*)(tvw + lane * 20);
        d4[0] = make_float4(tv[0], tv[1], tv[2], tv[3]);
        d4[1] = make_float4(tv[4], tv[5], tv[6], tv[7]);
        d4[2] = make_float4(tv[8], tv[9], tv[10], tv[11]);
        d4[3] = make_float4(tv[12], tv[13], tv[14], tv[15]);
    }
    float s = 0.f, q = 0.f;
#pragma unroll 4
    for (int f = 0; f < 64; ++f) {
        const float* wc = wcol + f * 20;
        const float4 w0 = *(const float4*)(wc + 0), w1 = *(const float4*)(wc + 4);
        const float4 w2 = *(const float4*)(wc + 8), w3 = *(const float4*)(wc + 12);
        float o = wc[16];
        o = fmaf(tv[0], w0.x, o);  o = fmaf(tv[1], w0.y, o);
        o = fmaf(tv[2], w0.z, o);  o = fmaf(tv[3], w0.w, o);
        o = fmaf(tv[4], w1.x, o);  o = fmaf(tv[5], w1.y, o);
        o = fmaf(tv[6], w1.z, o);  o = fmaf(tv[7], w1.w, o);
        o = fmaf(tv[8], w2.x, o);  o = fmaf(tv[9], w2.y, o);
        o = fmaf(tv[10], w2.z, o); o = fmaf(tv[11], w2.w, o);
        o = fmaf(tv[12], w3.x, o); o = fmaf(tv[13], w3.y, o);
        o = fmaf(tv[14], w3.z, o); o = fmaf(tv[15], w3.w, o);
        o = fmaxf(o, 0.f);
        s += o; q = fmaf(o, o, q);
    }
    {
        float m = s * 0.015625f;
        float va = q * 0.015625f - m * m;
        *(float2*)(mr + (wv * 64 + lane) * 2) = make_float2(m, rsqrtf(va + 1e-5f));
    }

    float wreg[16];
#pragma unroll
    for (int k = 0; k < 16; ++k) wreg[k] = W3a[k * 64 + lane];
    float bb = b3a[lane], gg = g3a[lane], bt = be3a[lane];
    int C0 = blockIdx.x * 16 + wv * 4;
#pragma unroll
    for (int cl = 0; cl < 4; ++cl) {
#pragma unroll
        for (int b2 = 0; b2 < 4; ++b2) {
            float acc = 0.f;
#pragma unroll
            for (int j = 0; j < 4; ++j) {
                int cb = (cl * 4 + j) * 4 + b2;
                const float* tp = tvw + cb * 20;
                const float4 a0 = *(const float4*)(tp + 0);
                const float4 a1 = *(const float4*)(tp + 4);
                const float4 a2 = *(const float4*)(tp + 8);
                const float4 a3 = *(const float4*)(tp + 12);
                float o = bb;
                o = fmaf(a0.x, wreg[0], o);  o = fmaf(a0.y, wreg[1], o);
                o = fmaf(a0.z, wreg[2], o);  o = fmaf(a0.w, wreg[3], o);
                o = fmaf(a1.x, wreg[4], o);  o = fmaf(a1.y, wreg[5], o);
                o = fmaf(a1.z, wreg[6], o);  o = fmaf(a1.w, wreg[7], o);
                o = fmaf(a2.x, wreg[8], o);  o = fmaf(a2.y, wreg[9], o);
                o = fmaf(a2.z, wreg[10], o); o = fmaf(a2.w, wreg[11], o);
                o = fmaf(a3.x, wreg[12], o); o = fmaf(a3.y, wreg[13], o);
                o = fmaf(a3.z, wreg[14], o); o = fmaf(a3.w, wreg[15], o);
                o = fmaxf(o, 0.f);
                const float2 mrv = *(const float2*)(mr + (wv * 64 + cb) * 2);
                float v = (o - mrv.x) * mrv.y;
                acc += fmaf(v, gg, bt);
            }
            h3p[((size_t)b2 * NCC + C0 + cl) * 64 + lane] = f2bf(acc * 0.25f);
        }
    }
}

// ---------------------------------------------------------------------------
// coarse-graph K=2 conv + relu + LN -> concat output.
// bf16 h input; BATCH-MAJOR group ordering so the concurrently-gathered
// region is one batch (3.1/6.3 MB) -> per-XCD L2-resident.
template <int FD>
__global__ __launch_bounds__(256) void k_coarse(
    const bfu* __restrict__ h, const int* __restrict__ idx, const float* __restrict__ w,
    const float* __restrict__ Wb, const float* __restrict__ bv, const float* __restrict__ gv,
    const float* __restrict__ bev, float* __restrict__ out) {
    constexpr int GPB = 256 / FD;
    __shared__ float ylds[GPB][2 * FD];
    int lane = threadIdx.x & (FD - 1);
    int grp = threadIdx.x / FD;

    float w0r[FD], w1r[FD];
#pragma unroll
    for (int u = 0; u < FD; ++u) {
        w0r[u] = Wb[u * FD + lane];
        w1r[u] = Wb[FD * FD + u * FD + lane];
    }
    float bb = bv[lane], gg = gv[lane], bt = bev[lane];

    int ngrp = gridDim.x * GPB;
    for (int g = blockIdx.x * GPB + grp; g < 4 * NCC; g += ngrp) {
        int b = g / NCC;              // batch-major: concurrent groups share batch
        int c = g - b * NCC;
        const bfu* hb = h + (size_t)b * NCC * FD;
        float y0 = bf2f(hb[(size_t)c * FD + lane]);
        float y1 = 0.f;
#pragma unroll
        for (int j = 0; j < 8; ++j) {
            int nj = idx[c * 8 + j];
            float wj = w[c * 8 + j];
            y1 = fmaf(wj, bf2f(hb[(size_t)nj * FD + lane]), y1);
        }
        ylds[grp][lane] = y0;
        ylds[grp][FD + lane] = y1;
        const float4* y4 = (const float4*)(&ylds[grp][0]);
        float o = bb;
#pragma unroll
        for (int u = 0; u < FD / 4; ++u) {
            float4 yv = y4[u];
            o = fmaf(yv.x, w0r[4 * u + 0], o);
            o = fmaf(yv.y, w0r[4 * u + 1], o);
            o = fmaf(yv.z, w0r[4 * u + 2], o);
            o = fmaf(yv.w, w0r[4 * u + 3], o);
        }
#pragma unroll
        for (int u = 0; u < FD / 4; ++u) {
            float4 yv = y4[FD / 4 + u];
            o = fmaf(yv.x, w1r[4 * u + 0], o);
            o = fmaf(yv.y, w1r[4 * u + 1], o);
            o = fmaf(yv.z, w1r[4 * u + 2], o);
            o = fmaf(yv.w, w1r[4 * u + 3], o);
        }
        o = fmaxf(o, 0.f);
        float s = o, q = o * o;
#pragma unroll
        for (int m = FD / 2; m >= 1; m >>= 1) {
            s += __shfl_xor(s, m, FD);
            q += __shfl_xor(q, m, FD);
        }
        float mu = s * (1.f / FD), va = q * (1.f / FD) - mu * mu;
        float r = (o - mu) * rsqrtf(va + 1e-5f) * gg + bt;
        out[((size_t)b * NCC + c) * 128 + lane] = r;
    }
}

// ---------------------------------------------------------------------------
extern "C" void kernel_launch(void* const* d_in, const int* in_sizes, int n_in,
                              void* d_out, int out_size, void* d_ws, size_t ws_size,
                              hipStream_t stream) {
    const float* maps = (const float*)d_in[0];
    const float* w8   = (const float*)d_in[1];
    const float* w20  = (const float*)d_in[2];
    const float* w8s  = (const float*)d_in[3];
    const int*   idx8  = (const int*)d_in[4];
    const int*   idx20 = (const int*)d_in[5];
    const int*   idx8s = (const int*)d_in[6];
    const float* W1a = (const float*)d_in[7];
    const float* b1a = (const float*)d_in[8];
    const float* g1a = (const float*)d_in[9];
    const float* be1a = (const float*)d_in[10];
    const float* W1b = (const float*)d_in[11];
    const float* b1b = (const float*)d_in[12];
    const float* g1b = (const float*)d_in[13];
    const float* be1b = (const float*)d_in[14];
    const float* W2a = (const float*)d_in[15];
    const float* b2a = (const float*)d_in[16];
    const float* g2a = (const float*)d_in[17];
    const float* be2a = (const float*)d_in[18];
    const float* W2b = (const float*)d_in[19];
    const float* b2b = (const float*)d_in[20];
    const float* g2b = (const float*)d_in[21];
    const float* be2b = (const float*)d_in[22];
    const float* W3a = (const float*)d_in[23];
    const float* b3a = (const float*)d_in[24];
    const float* g3a = (const float*)d_in[25];
    const float* be3a = (const float*)d_in[26];
    const float* W3b = (const float*)d_in[27];
    const float* b3b = (const float*)d_in[28];
    const float* g3b = (const float*)d_in[29];
    const float* be3b = (const float*)d_in[30];
    float* out = (float*)d_out;

    // workspace layout (floats), 151 MB total:
    //   xt       [0, 1572864)
    //   slot[i]  1572864*(1+i), i=0..6
    //   h1p(bf16) @ 12582912  [idx8T/w8T overlay: dead before epiA]
    //   h2p(bf16) @ 18874368
    //   h3p(bf16) @ 25165824  [idx20T/w20T overlay: dead before epiB]
    float* ws = (float*)d_ws;
    float* xt = ws;
    float* slot[7];
    for (int i = 0; i < 7; ++i) slot[i] = ws + (size_t)1572864 * (1 + i);
    bfu* h1p = (bfu*)(ws + (size_t)12582912);
    bfu* h2p = (bfu*)(ws + (size_t)18874368);
    bfu* h3p = (bfu*)(ws + (size_t)25165824);
    int*   idx8T  = (int*)(ws + 12582912);
    float* w8T    = ws + 12582912 + 1572864;
    int*   idx20T = (int*)(ws + 25165824);
    float* w20T   = ws + 25165824 + 3932160;

    dim3 blk(256);
    dim3 gN(NPIXF / 256);        // 768
    dim3 gL(2 * NPIXF / 256);    // 1536 (2 threads/node)
    dim3 gE(NPIXF / 64);         // 3072 (epilogues: 64 fine nodes/block)

    k_tiw<8><<<gN, blk, 0, stream>>>(idx8, w8, idx8T, w8T);
    k_tiw<20><<<gN, blk, 0, stream>>>(idx20, w20, idx20T, w20T);
    k_transpose2<<<gN, blk, 0, stream>>>(maps, xt);

    // 8-neighbor chain: T1..T5
    k_lap2<8, true><<<gL, blk, 0, stream>>>(xt, nullptr, slot[0], idx8T, w8T);
    k_lap2<8, false><<<gL, blk, 0, stream>>>(slot[0], xt, slot[1], idx8T, w8T);
    k_lap2<8, false><<<gL, blk, 0, stream>>>(slot[1], slot[0], slot[2], idx8T, w8T);
    k_lap2<8, false><<<gL, blk, 0, stream>>>(slot[2], slot[1], slot[3], idx8T, w8T);
    k_lap2<8, false><<<gL, blk, 0, stream>>>(slot[3], slot[2], slot[4], idx8T, w8T);

    k_epiA<<<gE, blk, 0, stream>>>(xt, slot[0], slot[1], slot[2], slot[3], slot[4],
                                   W1a, b1a, g1a, be1a, W2a, b2a, g2a, be2a, h1p, h2p);

    // 20-neighbor chain: T1..T7
    k_lap2<20, true><<<gL, blk, 0, stream>>>(xt, nullptr, slot[0], idx20T, w20T);
    k_lap2<20, false><<<gL, blk, 0, stream>>>(slot[0], xt, slot[1], idx20T, w20T);
    k_lap2<20, false><<<gL, blk, 0, stream>>>(slot[1], slot[0], slot[2], idx20T, w20T);
    k_lap2<20, false><<<gL, blk, 0, stream>>>(slot[2], slot[1], slot[3], idx20T, w20T);
    k_lap2<20, false><<<gL, blk, 0, stream>>>(slot[3], slot[2], slot[4], idx20T, w20T);
    k_lap2<20, false><<<gL, blk, 0, stream>>>(slot[4], slot[3], slot[5], idx20T, w20T);
    k_lap2<20, false><<<gL, blk, 0, stream>>>(slot[5], slot[4], slot[6], idx20T, w20T);

    k_epiB<<<gE, blk, 0, stream>>>(xt, slot[0], slot[1], slot[2], slot[3], slot[4],
                                   slot[5], slot[6], W3a, b3a, g3a, be3a, h3p);

    // coarse graph convs -> concatenated output [B][NCC][128]
    k_coarse<32><<<2048, blk, 0, stream>>>(h1p, idx8s, w8s, W1b, b1b, g1b, be1b, out + 0);
    k_coarse<32><<<2048, blk, 0, stream>>>(h2p, idx8s, w8s, W2b, b2b, g2b, be2b, out + 32);
    k_coarse<64><<<2048, blk, 0, stream>>>(h3p, idx8s, w8s, W3b, b3b, g3b, be3b, out + 64);
}

// Round 6
// 814.423 us; speedup vs baseline: 1.5784x; 1.0937x over previous
//
#include <hip/hip_runtime.h>
#include <math.h>

#define NPIXF 196608   // fine nodes (12*128*128)
#define NCC   49152    // coarse nodes (NPIXF/4)
// fine T layout: [N][B*2] = 8 floats (32B) per node  (b major, ch minor)
// coarse h layout: [c][b][f] bf16  (c-major so one wave gathers a full node)

typedef unsigned short bfu;

__device__ inline bfu f2bf(float x) {
    union { float f; unsigned u; } v; v.f = x;
    unsigned r = v.u + 0x7fff + ((v.u >> 16) & 1);   // RNE
    return (bfu)(r >> 16);
}
__device__ inline float bf2f(bfu b) {
    union { unsigned u; float f; } v; v.u = ((unsigned)b) << 16;
    return v.f;
}

// ---------------------------------------------------------------------------
// transpose idx/w [N][NN] -> [NN][N] so lap streams are coalesced
template <int NN>
__global__ __launch_bounds__(256) void k_tiw(const int* __restrict__ idx,
                                             const float* __restrict__ w,
                                             int* __restrict__ idxT,
                                             float* __restrict__ wT) {
    int n = blockIdx.x * 256 + threadIdx.x;
    if (n >= NPIXF) return;
#pragma unroll
    for (int j = 0; j < NN; ++j) {
        idxT[j * NPIXF + n] = idx[(size_t)n * NN + j];
        wT[j * NPIXF + n]   = w[(size_t)n * NN + j];
    }
}

// transpose maps [B][N][2] -> xt [N][B][2]
__global__ __launch_bounds__(256) void k_transpose2(const float* __restrict__ maps,
                                                    float* __restrict__ xt) {
    int n = blockIdx.x * 256 + threadIdx.x;
    if (n >= NPIXF) return;
    const float2* m2 = (const float2*)maps;
    float2 v0 = m2[0 * NPIXF + n];
    float2 v1 = m2[1 * NPIXF + n];
    float2 v2 = m2[2 * NPIXF + n];
    float2 v3 = m2[3 * NPIXF + n];
    float4* o = (float4*)(xt + (size_t)n * 8);
    o[0] = make_float4(v0.x, v0.y, v1.x, v1.y);
    o[1] = make_float4(v2.x, v2.y, v3.x, v3.y);
}

// ---------------------------------------------------------------------------
// one Chebyshev step; 2 threads per node (each owns a 16B half of the payload)
template <int NN, bool FIRST>
__global__ __launch_bounds__(256) void k_lap2(const float* __restrict__ src,
                                              const float* __restrict__ src2,
                                              float* __restrict__ dst,
                                              const int* __restrict__ idxT,
                                              const float* __restrict__ wT) {
    int t = blockIdx.x * 256 + threadIdx.x;
    int n = t >> 1;
    int h = (t & 1) * 4;
    if (n >= NPIXF) return;
    int nj[NN]; float wj[NN];
#pragma unroll
    for (int j = 0; j < NN; ++j) {
        nj[j] = idxT[j * NPIXF + n];
        wj[j] = wT[j * NPIXF + n];
    }
    float4 a = make_float4(0.f, 0.f, 0.f, 0.f);
#pragma unroll
    for (int j = 0; j < NN; ++j) {
        const float4 x = *(const float4*)(src + (size_t)nj[j] * 8 + h);
        a.x = fmaf(wj[j], x.x, a.x);
        a.y = fmaf(wj[j], x.y, a.y);
        a.z = fmaf(wj[j], x.z, a.z);
        a.w = fmaf(wj[j], x.w, a.w);
    }
    float4 o;
    if (FIRST) {
        o = a;
    } else {
        float4 qv = *(const float4*)(src2 + (size_t)n * 8 + h);
        o = make_float4(2.f * a.x - qv.x, 2.f * a.y - qv.y,
                        2.f * a.z - qv.z, 2.f * a.w - qv.w);
    }
    *(float4*)(dst + (size_t)n * 8 + h) = o;
}

// ---------------------------------------------------------------------------
// epilogue branches 1&2 (F=32): sum_k T_k W_k + b -> relu -> LN -> pool4
// writes fused bf16 h12[c][b][64]  (branch1 -> f 0..31, branch2 -> f 32..63)
__global__ __launch_bounds__(256) void k_epiA(
    const float* __restrict__ t0, const float* __restrict__ t1, const float* __restrict__ t2,
    const float* __restrict__ t3, const float* __restrict__ t4, const float* __restrict__ t5,
    const float* __restrict__ W1a, const float* __restrict__ b1a,
    const float* __restrict__ g1a, const float* __restrict__ be1a,
    const float* __restrict__ W2a, const float* __restrict__ b2a,
    const float* __restrict__ g2a, const float* __restrict__ be2a,
    bfu* __restrict__ h12p) {
    __shared__ float wcA[32 * 24];        // [f][0..7 w1 | 8..19 w2 | 20 b1 | 21 b2]
    __shared__ float tvlds[4 * 64 * 12];  // per wave: 64 cb rows of 12
    __shared__ float mrA[256 * 4];        // [cb][m1,r1,m2,r2]

    int tid = threadIdx.x;
    if (tid < 64) {               // W1a: 8x32
        int kk = tid >> 3, f4 = (tid & 7) * 4;
        float4 v = *(const float4*)(W1a + kk * 32 + f4);
        wcA[(f4 + 0) * 24 + kk] = v.x; wcA[(f4 + 1) * 24 + kk] = v.y;
        wcA[(f4 + 2) * 24 + kk] = v.z; wcA[(f4 + 3) * 24 + kk] = v.w;
    } else if (tid < 160) {       // W2a: 12x32
        int u = tid - 64;
        int kk = u >> 3, f4 = (u & 7) * 4;
        float4 v = *(const float4*)(W2a + kk * 32 + f4);
        wcA[(f4 + 0) * 24 + 8 + kk] = v.x; wcA[(f4 + 1) * 24 + 8 + kk] = v.y;
        wcA[(f4 + 2) * 24 + 8 + kk] = v.z; wcA[(f4 + 3) * 24 + 8 + kk] = v.w;
    } else if (tid < 192) {
        wcA[(tid - 160) * 24 + 20] = b1a[tid - 160];
    } else if (tid < 224) {
        wcA[(tid - 192) * 24 + 21] = b2a[tid - 192];
    }
    __syncthreads();

    int lane = tid & 63;
    int wv = tid >> 6;
    int b = lane & 3;
    int n = blockIdx.x * 64 + wv * 16 + (lane >> 2);

    float tv[12];
    {
        const float* tp[6] = {t0, t1, t2, t3, t4, t5};
#pragma unroll
        for (int t = 0; t < 6; ++t) {
            float2 v = *(const float2*)(tp[t] + (size_t)n * 8 + b * 2);
            tv[2 * t] = v.x; tv[2 * t + 1] = v.y;
        }
    }
    float* tvw = tvlds + wv * (64 * 12);
    {
        float4* d4 = (float4*)(tvw + lane * 12);
        d4[0] = make_float4(tv[0], tv[1], tv[2], tv[3]);
        d4[1] = make_float4(tv[4], tv[5], tv[6], tv[7]);
        d4[2] = make_float4(tv[8], tv[9], tv[10], tv[11]);
    }
    float s1 = 0.f, q1 = 0.f, s2 = 0.f, q2 = 0.f;
#pragma unroll 4
    for (int f = 0; f < 32; ++f) {
        const float* wc = wcA + f * 24;
        const float4 u0 = *(const float4*)(wc + 0), u1 = *(const float4*)(wc + 4);
        const float4 v0 = *(const float4*)(wc + 8), v1 = *(const float4*)(wc + 12),
                     v2 = *(const float4*)(wc + 16);
        float o1 = wc[20];
        o1 = fmaf(tv[0], u0.x, o1); o1 = fmaf(tv[1], u0.y, o1);
        o1 = fmaf(tv[2], u0.z, o1); o1 = fmaf(tv[3], u0.w, o1);
        o1 = fmaf(tv[4], u1.x, o1); o1 = fmaf(tv[5], u1.y, o1);
        o1 = fmaf(tv[6], u1.z, o1); o1 = fmaf(tv[7], u1.w, o1);
        o1 = fmaxf(o1, 0.f);
        float o2 = wc[21];
        o2 = fmaf(tv[0], v0.x, o2); o2 = fmaf(tv[1], v0.y, o2);
        o2 = fmaf(tv[2], v0.z, o2); o2 = fmaf(tv[3], v0.w, o2);
        o2 = fmaf(tv[4], v1.x, o2); o2 = fmaf(tv[5], v1.y, o2);
        o2 = fmaf(tv[6], v1.z, o2); o2 = fmaf(tv[7], v1.w, o2);
        o2 = fmaf(tv[8], v2.x, o2); o2 = fmaf(tv[9], v2.y, o2);
        o2 = fmaf(tv[10], v2.z, o2); o2 = fmaf(tv[11], v2.w, o2);
        o2 = fmaxf(o2, 0.f);
        s1 += o1; q1 = fmaf(o1, o1, q1);
        s2 += o2; q2 = fmaf(o2, o2, q2);
    }
    {
        float m1 = s1 * 0.03125f, va1 = q1 * 0.03125f - m1 * m1;
        float m2 = s2 * 0.03125f, va2 = q2 * 0.03125f - m2 * m2;
        *(float4*)(mrA + (wv * 64 + lane) * 4) =
            make_float4(m1, rsqrtf(va1 + 1e-5f), m2, rsqrtf(va2 + 1e-5f));
    }
    // wave-local LDS: same wave wrote what it reads.

    int f = lane & 31;
    int br = lane >> 5;
    float wreg[12];
#pragma unroll
    for (int k = 0; k < 12; ++k) {
        float w1v = (k < 8) ? W1a[k * 32 + f] : 0.f;
        wreg[k] = br ? W2a[k * 32 + f] : w1v;
    }
    float bb = br ? b2a[f] : b1a[f];
    float gg = br ? g2a[f] : g1a[f];
    float bt = br ? be2a[f] : be1a[f];
    int C0 = blockIdx.x * 16 + wv * 4;
#pragma unroll
    for (int cl = 0; cl < 4; ++cl) {
#pragma unroll
        for (int b2 = 0; b2 < 4; ++b2) {
            float acc = 0.f;
#pragma unroll
            for (int j = 0; j < 4; ++j) {
                int cb = (cl * 4 + j) * 4 + b2;
                const float* tp = tvw + cb * 12;
                const float4 a0 = *(const float4*)(tp + 0);
                const float4 a1 = *(const float4*)(tp + 4);
                const float4 a2 = *(const float4*)(tp + 8);
                float o = bb;
                o = fmaf(a0.x, wreg[0], o); o = fmaf(a0.y, wreg[1], o);
                o = fmaf(a0.z, wreg[2], o); o = fmaf(a0.w, wreg[3], o);
                o = fmaf(a1.x, wreg[4], o); o = fmaf(a1.y, wreg[5], o);
                o = fmaf(a1.z, wreg[6], o); o = fmaf(a1.w, wreg[7], o);
                o = fmaf(a2.x, wreg[8], o); o = fmaf(a2.y, wreg[9], o);
                o = fmaf(a2.z, wreg[10], o); o = fmaf(a2.w, wreg[11], o);
                o = fmaxf(o, 0.f);
                const float4 mr4 = *(const float4*)(mrA + (wv * 64 + cb) * 4);
                float m = br ? mr4.z : mr4.x;
                float r = br ? mr4.w : mr4.y;
                float v = (o - m) * r;
                acc += fmaf(v, gg, bt);
            }
            h12p[((size_t)(C0 + cl) * 4 + b2) * 64 + br * 32 + f] = f2bf(acc * 0.25f);
        }
    }
}

// ---------------------------------------------------------------------------
// epilogue branch 3 (F=64) — writes bf16 h3[c][b][64]
__global__ __launch_bounds__(256) void k_epiB(
    const float* __restrict__ t0, const float* __restrict__ t1, const float* __restrict__ t2,
    const float* __restrict__ t3, const float* __restrict__ t4, const float* __restrict__ t5,
    const float* __restrict__ t6, const float* __restrict__ t7,
    const float* __restrict__ W3a, const float* __restrict__ b3a,
    const float* __restrict__ g3a, const float* __restrict__ be3a,
    bfu* __restrict__ h3p) {
    __shared__ float wcol[64 * 20];       // [f][16 w | bias at 16] pad 20
    __shared__ float tvlds[4 * 64 * 20];
    __shared__ float mr[256 * 2];

    int tid = threadIdx.x;
    {
        int kk = tid >> 4, f4 = (tid & 15) * 4;
        float4 v = *(const float4*)(W3a + kk * 64 + f4);
        wcol[(f4 + 0) * 20 + kk] = v.x; wcol[(f4 + 1) * 20 + kk] = v.y;
        wcol[(f4 + 2) * 20 + kk] = v.z; wcol[(f4 + 3) * 20 + kk] = v.w;
        if (tid < 64) wcol[tid * 20 + 16] = b3a[tid];
    }
    __syncthreads();

    int lane = tid & 63;
    int wv = tid >> 6;
    int b = lane & 3;
    int n = blockIdx.x * 64 + wv * 16 + (lane >> 2);

    float tv[16];
    {
        const float* tp[8] = {t0, t1, t2, t3, t4, t5, t6, t7};
#pragma unroll
        for (int t = 0; t < 8; ++t) {
            float2 v = *(const float2*)(tp[t] + (size_t)n * 8 + b * 2);
            tv[2 * t] = v.x; tv[2 * t + 1] = v.y;
        }
    }
    float* tvw = tvlds + wv * (64 * 20);
    {
        float4* d4 = (float4*)(tvw + lane * 20);
        d4[0] = make_float4(tv[0], tv[1], tv[2], tv[3]);
        d4[1] = make_float4(tv[4], tv[5], tv[6], tv[7]);
        d4[2] = make_float4(tv[8], tv[9], tv[10], tv[11]);
        d4[3] = make_float4(tv[12], tv[13], tv[14], tv[15]);
    }
    float s = 0.f, q = 0.f;
#pragma unroll 4
    for (int f = 0; f < 64; ++f) {
        const float* wc = wcol + f * 20;
        const float4 w0 = *(const float4*)(wc + 0), w1 = *(const float4*)(wc + 4);
        const float4 w2 = *(const float4*)(wc + 8), w3 = *(const float4*)(wc + 12);
        float o = wc[16];
        o = fmaf(tv[0], w0.x, o);  o = fmaf(tv[1], w0.y, o);
        o = fmaf(tv[2], w0.z, o);  o = fmaf(tv[3], w0.w, o);
        o = fmaf(tv[4], w1.x, o);  o = fmaf(tv[5], w1.y, o);
        o = fmaf(tv[6], w1.z, o);  o = fmaf(tv[7], w1.w, o);
        o = fmaf(tv[8], w2.x, o);  o = fmaf(tv[9], w2.y, o);
        o = fmaf(tv[10], w2.z, o); o = fmaf(tv[11], w2.w, o);
        o = fmaf(tv[12], w3.x, o); o = fmaf(tv[13], w3.y, o);
        o = fmaf(tv[14], w3.z, o); o = fmaf(tv[15], w3.w, o);
        o = fmaxf(o, 0.f);
        s += o; q = fmaf(o, o, q);
    }
    {
        float m = s * 0.015625f;
        float va = q * 0.015625f - m * m;
        *(float2*)(mr + (wv * 64 + lane) * 2) = make_float2(m, rsqrtf(va + 1e-5f));
    }

    float wreg[16];
#pragma unroll
    for (int k = 0; k < 16; ++k) wreg[k] = W3a[k * 64 + lane];
    float bb = b3a[lane], gg = g3a[lane], bt = be3a[lane];
    int C0 = blockIdx.x * 16 + wv * 4;
#pragma unroll
    for (int cl = 0; cl < 4; ++cl) {
#pragma unroll
        for (int b2 = 0; b2 < 4; ++b2) {
            float acc = 0.f;
#pragma unroll
            for (int j = 0; j < 4; ++j) {
                int cb = (cl * 4 + j) * 4 + b2;
                const float* tp = tvw + cb * 20;
                const float4 a0 = *(const float4*)(tp + 0);
                const float4 a1 = *(const float4*)(tp + 4);
                const float4 a2 = *(const float4*)(tp + 8);
                const float4 a3 = *(const float4*)(tp + 12);
                float o = bb;
                o = fmaf(a0.x, wreg[0], o);  o = fmaf(a0.y, wreg[1], o);
                o = fmaf(a0.z, wreg[2], o);  o = fmaf(a0.w, wreg[3], o);
                o = fmaf(a1.x, wreg[4], o);  o = fmaf(a1.y, wreg[5], o);
                o = fmaf(a1.z, wreg[6], o);  o = fmaf(a1.w, wreg[7], o);
                o = fmaf(a2.x, wreg[8], o);  o = fmaf(a2.y, wreg[9], o);
                o = fmaf(a2.z, wreg[10], o); o = fmaf(a2.w, wreg[11], o);
                o = fmaf(a3.x, wreg[12], o); o = fmaf(a3.y, wreg[13], o);
                o = fmaf(a3.z, wreg[14], o); o = fmaf(a3.w, wreg[15], o);
                o = fmaxf(o, 0.f);
                const float2 mrv = *(const float2*)(mr + (wv * 64 + cb) * 2);
                float v = (o - mrv.x) * mrv.y;
                acc += fmaf(v, gg, bt);
            }
            h3p[((size_t)(C0 + cl) * 4 + b2) * 64 + lane] = f2bf(acc * 0.25f);
        }
    }
}

// ---------------------------------------------------------------------------
// fused coarse conv for branches 1&2.  h12[c][b][64] bf16; ONE WAVE per c.
// gather: 8 wave-wide 512B loads; matvec via wave-local LDS; LN width 32.
__global__ __launch_bounds__(256, 4) void k_coarse12(
    const bfu* __restrict__ h12, const int* __restrict__ idx, const float* __restrict__ w,
    const float* __restrict__ W1b, const float* __restrict__ b1b,
    const float* __restrict__ g1b, const float* __restrict__ be1b,
    const float* __restrict__ W2b, const float* __restrict__ b2b,
    const float* __restrict__ g2b, const float* __restrict__ be2b,
    float* __restrict__ out) {
    __shared__ float ylds[4][2][256];   // [wave][y0|y1][b*64+f]
    int tid = threadIdx.x;
    int lane = tid & 63;
    int wv = tid >> 6;
    int c = blockIdx.x * 4 + wv;

    // weight columns: lane<32 -> branch1 (f'=lane), lane>=32 -> branch2 (f'=lane-32)
    int fp = lane & 31;
    const float* Wb = (lane < 32) ? W1b : W2b;
    float wa[32], wb_[32];
#pragma unroll
    for (int k = 0; k < 32; ++k) {
        wa[k]  = Wb[k * 32 + fp];
        wb_[k] = Wb[1024 + k * 32 + fp];
    }
    float bb = (lane < 32) ? b1b[fp] : b2b[fp];
    float gg = (lane < 32) ? g1b[fp] : g2b[fp];
    float bt = (lane < 32) ? be1b[fp] : be2b[fp];

    int iv = 0; float wvv = 0.f;
    if (lane < 8) { iv = idx[c * 8 + lane]; wvv = w[c * 8 + lane]; }

    const ushort4* hb = (const ushort4*)h12;   // 8B granules; c block = 64 granules
    ushort4 v0 = hb[(size_t)c * 64 + lane];
    float a0 = 0.f, a1 = 0.f, a2 = 0.f, a3 = 0.f;
#pragma unroll
    for (int j = 0; j < 8; ++j) {
        int nj = __shfl(iv, j);
        float wj = __shfl(wvv, j);
        ushort4 x = hb[(size_t)nj * 64 + lane];
        a0 = fmaf(wj, bf2f(x.x), a0);
        a1 = fmaf(wj, bf2f(x.y), a1);
        a2 = fmaf(wj, bf2f(x.z), a2);
        a3 = fmaf(wj, bf2f(x.w), a3);
    }
    int yoff = lane * 4;   // = (b*64 + f) base for this lane's 4 values
    *(float4*)&ylds[wv][0][yoff] = make_float4(bf2f(v0.x), bf2f(v0.y), bf2f(v0.z), bf2f(v0.w));
    *(float4*)&ylds[wv][1][yoff] = make_float4(a0, a1, a2, a3);
    // wave-local LDS: same wave wrote what it reads.

    int half = (lane >> 5) * 32;
#pragma unroll
    for (int b = 0; b < 4; ++b) {
        const float* y0p = &ylds[wv][0][b * 64 + half];
        const float* y1p = &ylds[wv][1][b * 64 + half];
        float o = bb;
#pragma unroll
        for (int u = 0; u < 8; ++u) {
            float4 yv0 = *(const float4*)(y0p + 4 * u);
            float4 yv1 = *(const float4*)(y1p + 4 * u);
            o = fmaf(yv0.x, wa[4 * u + 0], o);
            o = fmaf(yv0.y, wa[4 * u + 1], o);
            o = fmaf(yv0.z, wa[4 * u + 2], o);
            o = fmaf(yv0.w, wa[4 * u + 3], o);
            o = fmaf(yv1.x, wb_[4 * u + 0], o);
            o = fmaf(yv1.y, wb_[4 * u + 1], o);
            o = fmaf(yv1.z, wb_[4 * u + 2], o);
            o = fmaf(yv1.w, wb_[4 * u + 3], o);
        }
        o = fmaxf(o, 0.f);
        float s = o, q = o * o;
#pragma unroll
        for (int m = 16; m >= 1; m >>= 1) {
            s += __shfl_xor(s, m, 32);
            q += __shfl_xor(q, m, 32);
        }
        float mu = s * 0.03125f, va = q * 0.03125f - mu * mu;
        float r = (o - mu) * rsqrtf(va + 1e-5f) * gg + bt;
        out[((size_t)b * NCC + c) * 128 + lane] = r;   // cols 0..63 = br1|br2
    }
}

// ---------------------------------------------------------------------------
// coarse conv branch 3. h3[c][b][64] bf16; one wave per c; LN width 64.
__global__ __launch_bounds__(256, 2) void k_coarse3(
    const bfu* __restrict__ h3, const int* __restrict__ idx, const float* __restrict__ w,
    const float* __restrict__ W3b, const float* __restrict__ b3b,
    const float* __restrict__ g3b, const float* __restrict__ be3b,
    float* __restrict__ out) {
    __shared__ float ylds[4][2][256];
    int tid = threadIdx.x;
    int lane = tid & 63;
    int wv = tid >> 6;
    int c = blockIdx.x * 4 + wv;

    float wa[64], wb_[64];
#pragma unroll
    for (int k = 0; k < 64; ++k) {
        wa[k]  = W3b[k * 64 + lane];
        wb_[k] = W3b[4096 + k * 64 + lane];
    }
    float bb = b3b[lane], gg = g3b[lane], bt = be3b[lane];

    int iv = 0; float wvv = 0.f;
    if (lane < 8) { iv = idx[c * 8 + lane]; wvv = w[c * 8 + lane]; }

    const ushort4* hb = (const ushort4*)h3;
    ushort4 v0 = hb[(size_t)c * 64 + lane];
    float a0 = 0.f, a1 = 0.f, a2 = 0.f, a3 = 0.f;
#pragma unroll
    for (int j = 0; j < 8; ++j) {
        int nj = __shfl(iv, j);
        float wj = __shfl(wvv, j);
        ushort4 x = hb[(size_t)nj * 64 + lane];
        a0 = fmaf(wj, bf2f(x.x), a0);
        a1 = fmaf(wj, bf2f(x.y), a1);
        a2 = fmaf(wj, bf2f(x.z), a2);
        a3 = fmaf(wj, bf2f(x.w), a3);
    }
    int yoff = lane * 4;
    *(float4*)&ylds[wv][0][yoff] = make_float4(bf2f(v0.x), bf2f(v0.y), bf2f(v0.z), bf2f(v0.w));
    *(float4*)&ylds[wv][1][yoff] = make_float4(a0, a1, a2, a3);

#pragma unroll
    for (int b = 0; b < 4; ++b) {
        const float* y0p = &ylds[wv][0][b * 64];
        const float* y1p = &ylds[wv][1][b * 64];
        float o = bb;
#pragma unroll
        for (int u = 0; u < 16; ++u) {
            float4 yv0 = *(const float4*)(y0p + 4 * u);
            float4 yv1 = *(const float4*)(y1p + 4 * u);
            o = fmaf(yv0.x, wa[4 * u + 0], o);
            o = fmaf(yv0.y, wa[4 * u + 1], o);
            o = fmaf(yv0.z, wa[4 * u + 2], o);
            o = fmaf(yv0.w, wa[4 * u + 3], o);
            o = fmaf(yv1.x, wb_[4 * u + 0], o);
            o = fmaf(yv1.y, wb_[4 * u + 1], o);
            o = fmaf(yv1.z, wb_[4 * u + 2], o);
            o = fmaf(yv1.w, wb_[4 * u + 3], o);
        }
        o = fmaxf(o, 0.f);
        float s = o, q = o * o;
#pragma unroll
        for (int m = 32; m >= 1; m >>= 1) {
            s += __shfl_xor(s, m, 64);
            q += __shfl_xor(q, m, 64);
        }
        float mu = s * 0.015625f, va = q * 0.015625f - mu * mu;
        float r = (o - mu) * rsqrtf(va + 1e-5f) * gg + bt;
        out[((size_t)b * NCC + c) * 128 + 64 + lane] = r;
    }
}

// ---------------------------------------------------------------------------
extern "C" void kernel_launch(void* const* d_in, const int* in_sizes, int n_in,
                              void* d_out, int out_size, void* d_ws, size_t ws_size,
                              hipStream_t stream) {
    const float* maps = (const float*)d_in[0];
    const float* w8   = (const float*)d_in[1];
    const float* w20  = (const float*)d_in[2];
    const float* w8s  = (const float*)d_in[3];
    const int*   idx8  = (const int*)d_in[4];
    const int*   idx20 = (const int*)d_in[5];
    const int*   idx8s = (const int*)d_in[6];
    const float* W1a = (const float*)d_in[7];
    const float* b1a = (const float*)d_in[8];
    const float* g1a = (const float*)d_in[9];
    const float* be1a = (const float*)d_in[10];
    const float* W1b = (const float*)d_in[11];
    const float* b1b = (const float*)d_in[12];
    const float* g1b = (const float*)d_in[13];
    const float* be1b = (const float*)d_in[14];
    const float* W2a = (const float*)d_in[15];
    const float* b2a = (const float*)d_in[16];
    const float* g2a = (const float*)d_in[17];
    const float* be2a = (const float*)d_in[18];
    const float* W2b = (const float*)d_in[19];
    const float* b2b = (const float*)d_in[20];
    const float* g2b = (const float*)d_in[21];
    const float* be2b = (const float*)d_in[22];
    const float* W3a = (const float*)d_in[23];
    const float* b3a = (const float*)d_in[24];
    const float* g3a = (const float*)d_in[25];
    const float* be3a = (const float*)d_in[26];
    const float* W3b = (const float*)d_in[27];
    const float* b3b = (const float*)d_in[28];
    const float* g3b = (const float*)d_in[29];
    const float* be3b = (const float*)d_in[30];
    float* out = (float*)d_out;

    // workspace (floats):
    //   xt       [0, 1572864)
    //   slot[i]  1572864*(1+i), i=0..6
    //   h12p(bf16, 25MB) @ 12582912  [idx8T/w8T overlay: dead before epiA]
    //   h3p (bf16, 25MB) @ 25165824  [idx20T/w20T overlay: dead before epiB]
    float* ws = (float*)d_ws;
    float* xt = ws;
    float* slot[7];
    for (int i = 0; i < 7; ++i) slot[i] = ws + (size_t)1572864 * (1 + i);
    bfu* h12p = (bfu*)(ws + (size_t)12582912);
    bfu* h3p  = (bfu*)(ws + (size_t)25165824);
    int*   idx8T  = (int*)(ws + 12582912);
    float* w8T    = ws + 12582912 + 1572864;
    int*   idx20T = (int*)(ws + 25165824);
    float* w20T   = ws + 25165824 + 3932160;

    dim3 blk(256);
    dim3 gN(NPIXF / 256);        // 768
    dim3 gL(2 * NPIXF / 256);    // 1536 (2 threads/node)
    dim3 gE(NPIXF / 64);         // 3072 (epilogues: 64 fine nodes/block)
    dim3 gC(NCC / 4);            // 12288 (coarse: 1 wave/node, 4 waves/block)

    k_tiw<8><<<gN, blk, 0, stream>>>(idx8, w8, idx8T, w8T);
    k_tiw<20><<<gN, blk, 0, stream>>>(idx20, w20, idx20T, w20T);
    k_transpose2<<<gN, blk, 0, stream>>>(maps, xt);

    // 8-neighbor chain: T1..T5
    k_lap2<8, true><<<gL, blk, 0, stream>>>(xt, nullptr, slot[0], idx8T, w8T);
    k_lap2<8, false><<<gL, blk, 0, stream>>>(slot[0], xt, slot[1], idx8T, w8T);
    k_lap2<8, false><<<gL, blk, 0, stream>>>(slot[1], slot[0], slot[2], idx8T, w8T);
    k_lap2<8, false><<<gL, blk, 0, stream>>>(slot[2], slot[1], slot[3], idx8T, w8T);
    k_lap2<8, false><<<gL, blk, 0, stream>>>(slot[3], slot[2], slot[4], idx8T, w8T);

    k_epiA<<<gE, blk, 0, stream>>>(xt, slot[0], slot[1], slot[2], slot[3], slot[4],
                                   W1a, b1a, g1a, be1a, W2a, b2a, g2a, be2a, h12p);

    // 20-neighbor chain: T1..T7
    k_lap2<20, true><<<gL, blk, 0, stream>>>(xt, nullptr, slot[0], idx20T, w20T);
    k_lap2<20, false><<<gL, blk, 0, stream>>>(slot[0], xt, slot[1], idx20T, w20T);
    k_lap2<20, false><<<gL, blk, 0, stream>>>(slot[1], slot[0], slot[2], idx20T, w20T);
    k_lap2<20, false><<<gL, blk, 0, stream>>>(slot[2], slot[1], slot[3], idx20T, w20T);
    k_lap2<20, false><<<gL, blk, 0, stream>>>(slot[3], slot[2], slot[4], idx20T, w20T);
    k_lap2<20, false><<<gL, blk, 0, stream>>>(slot[4], slot[3], slot[5], idx20T, w20T);
    k_lap2<20, false><<<gL, blk, 0, stream>>>(slot[5], slot[4], slot[6], idx20T, w20T);

    k_epiB<<<gE, blk, 0, stream>>>(xt, slot[0], slot[1], slot[2], slot[3], slot[4],
                                   slot[5], slot[6], W3a, b3a, g3a, be3a, h3p);

    // coarse graph convs -> concatenated output [B][NCC][128]
    k_coarse12<<<gC, blk, 0, stream>>>(h12p, idx8s, w8s,
                                       W1b, b1b, g1b, be1b,
                                       W2b, b2b, g2b, be2b, out);
    k_coarse3<<<gC, blk, 0, stream>>>(h3p, idx8s, w8s, W3b, b3b, g3b, be3b, out);
}

// Round 7
// 596.844 us; speedup vs baseline: 2.1538x; 1.3645x over previous
//
#include <hip/hip_runtime.h>
#include <math.h>

#define NPIXF 196608   // fine nodes
#define NCC   49152    // coarse nodes
// fine T layout: [N][8] _Float16 (16B per node; b major, ch minor)
// coarse h layout: [c][b][f] bf16 (c-major: one wave gathers a full node)

typedef unsigned short bfu;
typedef __attribute__((ext_vector_type(8))) short s16x8;
typedef __attribute__((ext_vector_type(4))) float f32x4;

__device__ inline bfu f2bf(float x) {
    union { float f; unsigned u; } v; v.f = x;
    unsigned r = v.u + 0x7fff + ((v.u >> 16) & 1);   // RNE
    return (bfu)(r >> 16);
}
__device__ inline float bf2f(bfu b) {
    union { unsigned u; float f; } v; v.u = ((unsigned)b) << 16;
    return v.f;
}
__device__ inline float h2f(unsigned short h) {
    _Float16 x; __builtin_memcpy(&x, &h, 2); return (float)x;
}
__device__ inline unsigned short f2h(float f) {
    _Float16 x = (_Float16)f; unsigned short r; __builtin_memcpy(&r, &x, 2); return r;
}
union HPack { uint4 v; unsigned short u[8]; };

// ---------------------------------------------------------------------------
// transpose idx/w [N][NN] -> [NN][N]
template <int NN>
__global__ __launch_bounds__(256) void k_tiw(const int* __restrict__ idx,
                                             const float* __restrict__ w,
                                             int* __restrict__ idxT,
                                             float* __restrict__ wT) {
    int n = blockIdx.x * 256 + threadIdx.x;
    if (n >= NPIXF) return;
#pragma unroll
    for (int j = 0; j < NN; ++j) {
        idxT[j * NPIXF + n] = idx[(size_t)n * NN + j];
        wT[j * NPIXF + n]   = w[(size_t)n * NN + j];
    }
}

// transpose maps [B][N][2] fp32 -> xtH [N][8] f16
__global__ __launch_bounds__(256) void k_transposeH(const float* __restrict__ maps,
                                                    uint4* __restrict__ xtH) {
    int n = blockIdx.x * 256 + threadIdx.x;
    if (n >= NPIXF) return;
    const float2* m2 = (const float2*)maps;
    HPack p;
#pragma unroll
    for (int b = 0; b < 4; ++b) {
        float2 v = m2[(size_t)b * NPIXF + n];
        p.u[2 * b]     = f2h(v.x);
        p.u[2 * b + 1] = f2h(v.y);
    }
    xtH[n] = p.v;
}

// ---------------------------------------------------------------------------
// Chebyshev step, f16 payload, 1 thread/node. FIRST: dst=lap(src) else 2*lap-src2
template <int NN, bool FIRST>
__global__ __launch_bounds__(256) void k_lapH(const uint4* __restrict__ src,
                                              const uint4* __restrict__ src2,
                                              uint4* __restrict__ dst,
                                              const int* __restrict__ idxT,
                                              const float* __restrict__ wT) {
    int n = blockIdx.x * 256 + threadIdx.x;
    if (n >= NPIXF) return;
    int nj[NN]; float wj[NN];
#pragma unroll
    for (int j = 0; j < NN; ++j) {
        nj[j] = idxT[j * NPIXF + n];
        wj[j] = wT[j * NPIXF + n];
    }
    float a[8] = {0.f, 0.f, 0.f, 0.f, 0.f, 0.f, 0.f, 0.f};
#pragma unroll
    for (int j = 0; j < NN; ++j) {
        HPack x; x.v = src[nj[j]];
#pragma unroll
        for (int e = 0; e < 8; ++e) a[e] = fmaf(wj[j], h2f(x.u[e]), a[e]);
    }
    HPack o;
    if (FIRST) {
#pragma unroll
        for (int e = 0; e < 8; ++e) o.u[e] = f2h(a[e]);
    } else {
        HPack q; q.v = src2[n];
#pragma unroll
        for (int e = 0; e < 8; ++e) o.u[e] = f2h(2.f * a[e] - h2f(q.u[e]));
    }
    dst[n] = o.v;
}

// ---------------------------------------------------------------------------
// epilogue branches 1&2 (F=32) -> bf16 h12[c][b][64] (br1 f0..31 | br2 f32..63)
__global__ __launch_bounds__(256) void k_epiA(
    const unsigned* __restrict__ t0, const unsigned* __restrict__ t1,
    const unsigned* __restrict__ t2, const unsigned* __restrict__ t3,
    const unsigned* __restrict__ t4, const unsigned* __restrict__ t5,
    const float* __restrict__ W1a, const float* __restrict__ b1a,
    const float* __restrict__ g1a, const float* __restrict__ be1a,
    const float* __restrict__ W2a, const float* __restrict__ b2a,
    const float* __restrict__ g2a, const float* __restrict__ be2a,
    bfu* __restrict__ h12p) {
    __shared__ float wcA[32 * 24];
    __shared__ float tvlds[4 * 64 * 12];
    __shared__ float mrA[256 * 4];

    int tid = threadIdx.x;
    if (tid < 64) {
        int kk = tid >> 3, f4 = (tid & 7) * 4;
        float4 v = *(const float4*)(W1a + kk * 32 + f4);
        wcA[(f4 + 0) * 24 + kk] = v.x; wcA[(f4 + 1) * 24 + kk] = v.y;
        wcA[(f4 + 2) * 24 + kk] = v.z; wcA[(f4 + 3) * 24 + kk] = v.w;
    } else if (tid < 160) {
        int u = tid - 64;
        int kk = u >> 3, f4 = (u & 7) * 4;
        float4 v = *(const float4*)(W2a + kk * 32 + f4);
        wcA[(f4 + 0) * 24 + 8 + kk] = v.x; wcA[(f4 + 1) * 24 + 8 + kk] = v.y;
        wcA[(f4 + 2) * 24 + 8 + kk] = v.z; wcA[(f4 + 3) * 24 + 8 + kk] = v.w;
    } else if (tid < 192) {
        wcA[(tid - 160) * 24 + 20] = b1a[tid - 160];
    } else if (tid < 224) {
        wcA[(tid - 192) * 24 + 21] = b2a[tid - 192];
    }
    __syncthreads();

    int lane = tid & 63;
    int wv = tid >> 6;
    int b = lane & 3;
    int n = blockIdx.x * 64 + wv * 16 + (lane >> 2);

    float tv[12];
    {
        const unsigned* tp[6] = {t0, t1, t2, t3, t4, t5};
#pragma unroll
        for (int t = 0; t < 6; ++t) {
            unsigned v = tp[t][n * 4 + b];
            tv[2 * t]     = h2f((unsigned short)(v & 0xffff));
            tv[2 * t + 1] = h2f((unsigned short)(v >> 16));
        }
    }
    float* tvw = tvlds + wv * (64 * 12);
    {
        float4* d4 = (float4*)(tvw + lane * 12);
        d4[0] = make_float4(tv[0], tv[1], tv[2], tv[3]);
        d4[1] = make_float4(tv[4], tv[5], tv[6], tv[7]);
        d4[2] = make_float4(tv[8], tv[9], tv[10], tv[11]);
    }
    float s1 = 0.f, q1 = 0.f, s2 = 0.f, q2 = 0.f;
#pragma unroll 4
    for (int f = 0; f < 32; ++f) {
        const float* wc = wcA + f * 24;
        const float4 u0 = *(const float4*)(wc + 0), u1 = *(const float4*)(wc + 4);
        const float4 v0 = *(const float4*)(wc + 8), v1 = *(const float4*)(wc + 12),
                     v2 = *(const float4*)(wc + 16);
        float o1 = wc[20];
        o1 = fmaf(tv[0], u0.x, o1); o1 = fmaf(tv[1], u0.y, o1);
        o1 = fmaf(tv[2], u0.z, o1); o1 = fmaf(tv[3], u0.w, o1);
        o1 = fmaf(tv[4], u1.x, o1); o1 = fmaf(tv[5], u1.y, o1);
        o1 = fmaf(tv[6], u1.z, o1); o1 = fmaf(tv[7], u1.w, o1);
        o1 = fmaxf(o1, 0.f);
        float o2 = wc[21];
        o2 = fmaf(tv[0], v0.x, o2); o2 = fmaf(tv[1], v0.y, o2);
        o2 = fmaf(tv[2], v0.z, o2); o2 = fmaf(tv[3], v0.w, o2);
        o2 = fmaf(tv[4], v1.x, o2); o2 = fmaf(tv[5], v1.y, o2);
        o2 = fmaf(tv[6], v1.z, o2); o2 = fmaf(tv[7], v1.w, o2);
        o2 = fmaf(tv[8], v2.x, o2); o2 = fmaf(tv[9], v2.y, o2);
        o2 = fmaf(tv[10], v2.z, o2); o2 = fmaf(tv[11], v2.w, o2);
        o2 = fmaxf(o2, 0.f);
        s1 += o1; q1 = fmaf(o1, o1, q1);
        s2 += o2; q2 = fmaf(o2, o2, q2);
    }
    {
        float m1 = s1 * 0.03125f, va1 = q1 * 0.03125f - m1 * m1;
        float m2 = s2 * 0.03125f, va2 = q2 * 0.03125f - m2 * m2;
        *(float4*)(mrA + (wv * 64 + lane) * 4) =
            make_float4(m1, rsqrtf(va1 + 1e-5f), m2, rsqrtf(va2 + 1e-5f));
    }

    int f = lane & 31;
    int br = lane >> 5;
    float wreg[12];
#pragma unroll
    for (int k = 0; k < 12; ++k) {
        float w1v = (k < 8) ? W1a[k * 32 + f] : 0.f;
        wreg[k] = br ? W2a[k * 32 + f] : w1v;
    }
    float bb = br ? b2a[f] : b1a[f];
    float gg = br ? g2a[f] : g1a[f];
    float bt = br ? be2a[f] : be1a[f];
    int C0 = blockIdx.x * 16 + wv * 4;
#pragma unroll
    for (int cl = 0; cl < 4; ++cl) {
#pragma unroll
        for (int b2 = 0; b2 < 4; ++b2) {
            float acc = 0.f;
#pragma unroll
            for (int j = 0; j < 4; ++j) {
                int cb = (cl * 4 + j) * 4 + b2;
                const float* tp = tvw + cb * 12;
                const float4 a0 = *(const float4*)(tp + 0);
                const float4 a1 = *(const float4*)(tp + 4);
                const float4 a2 = *(const float4*)(tp + 8);
                float o = bb;
                o = fmaf(a0.x, wreg[0], o); o = fmaf(a0.y, wreg[1], o);
                o = fmaf(a0.z, wreg[2], o); o = fmaf(a0.w, wreg[3], o);
                o = fmaf(a1.x, wreg[4], o); o = fmaf(a1.y, wreg[5], o);
                o = fmaf(a1.z, wreg[6], o); o = fmaf(a1.w, wreg[7], o);
                o = fmaf(a2.x, wreg[8], o); o = fmaf(a2.y, wreg[9], o);
                o = fmaf(a2.z, wreg[10], o); o = fmaf(a2.w, wreg[11], o);
                o = fmaxf(o, 0.f);
                const float4 mr4 = *(const float4*)(mrA + (wv * 64 + cb) * 4);
                float m = br ? mr4.z : mr4.x;
                float r = br ? mr4.w : mr4.y;
                acc += fmaf((o - m) * r, gg, bt);
            }
            h12p[((size_t)(C0 + cl) * 4 + b2) * 64 + br * 32 + f] = f2bf(acc * 0.25f);
        }
    }
}

// ---------------------------------------------------------------------------
// epilogue branch 3 (F=64) -> bf16 h3[c][b][64]
__global__ __launch_bounds__(256) void k_epiB(
    const unsigned* __restrict__ t0, const unsigned* __restrict__ t1,
    const unsigned* __restrict__ t2, const unsigned* __restrict__ t3,
    const unsigned* __restrict__ t4, const unsigned* __restrict__ t5,
    const unsigned* __restrict__ t6, const unsigned* __restrict__ t7,
    const float* __restrict__ W3a, const float* __restrict__ b3a,
    const float* __restrict__ g3a, const float* __restrict__ be3a,
    bfu* __restrict__ h3p) {
    __shared__ float wcol[64 * 20];
    __shared__ float tvlds[4 * 64 * 20];
    __shared__ float mr[256 * 2];

    int tid = threadIdx.x;
    {
        int kk = tid >> 4, f4 = (tid & 15) * 4;
        float4 v = *(const float4*)(W3a + kk * 64 + f4);
        wcol[(f4 + 0) * 20 + kk] = v.x; wcol[(f4 + 1) * 20 + kk] = v.y;
        wcol[(f4 + 2) * 20 + kk] = v.z; wcol[(f4 + 3) * 20 + kk] = v.w;
        if (tid < 64) wcol[tid * 20 + 16] = b3a[tid];
    }
    __syncthreads();

    int lane = tid & 63;
    int wv = tid >> 6;
    int b = lane & 3;
    int n = blockIdx.x * 64 + wv * 16 + (lane >> 2);

    float tv[16];
    {
        const unsigned* tp[8] = {t0, t1, t2, t3, t4, t5, t6, t7};
#pragma unroll
        for (int t = 0; t < 8; ++t) {
            unsigned v = tp[t][n * 4 + b];
            tv[2 * t]     = h2f((unsigned short)(v & 0xffff));
            tv[2 * t + 1] = h2f((unsigned short)(v >> 16));
        }
    }
    float* tvw = tvlds + wv * (64 * 20);
    {
        float4* d4 = (float4*)(tvw + lane * 20);
        d4[0] = make_float4(tv[0], tv[1], tv[2], tv[3]);
        d4[1] = make_float4(tv[4], tv[5], tv[6], tv[7]);
        d4[2] = make_float4(tv[8], tv[9], tv[10], tv[11]);
        d4[3] = make_float4(tv[12], tv[13], tv[14], tv[15]);
    }
    float s = 0.f, q = 0.f;
#pragma unroll 4
    for (int f = 0; f < 64; ++f) {
        const float* wc = wcol + f * 20;
        const float4 w0 = *(const float4*)(wc + 0), w1 = *(const float4*)(wc + 4);
        const float4 w2 = *(const float4*)(wc + 8), w3 = *(const float4*)(wc + 12);
        float o = wc[16];
        o = fmaf(tv[0], w0.x, o);  o = fmaf(tv[1], w0.y, o);
        o = fmaf(tv[2], w0.z, o);  o = fmaf(tv[3], w0.w, o);
        o = fmaf(tv[4], w1.x, o);  o = fmaf(tv[5], w1.y, o);
        o = fmaf(tv[6], w1.z, o);  o = fmaf(tv[7], w1.w, o);
        o = fmaf(tv[8], w2.x, o);  o = fmaf(tv[9], w2.y, o);
        o = fmaf(tv[10], w2.z, o); o = fmaf(tv[11], w2.w, o);
        o = fmaf(tv[12], w3.x, o); o = fmaf(tv[13], w3.y, o);
        o = fmaf(tv[14], w3.z, o); o = fmaf(tv[15], w3.w, o);
        o = fmaxf(o, 0.f);
        s += o; q = fmaf(o, o, q);
    }
    {
        float m = s * 0.015625f;
        float va = q * 0.015625f - m * m;
        *(float2*)(mr + (wv * 64 + lane) * 2) = make_float2(m, rsqrtf(va + 1e-5f));
    }

    float wreg[16];
#pragma unroll
    for (int k = 0; k < 16; ++k) wreg[k] = W3a[k * 64 + lane];
    float bb = b3a[lane], gg = g3a[lane], bt = be3a[lane];
    int C0 = blockIdx.x * 16 + wv * 4;
#pragma unroll
    for (int cl = 0; cl < 4; ++cl) {
#pragma unroll
        for (int b2 = 0; b2 < 4; ++b2) {
            float acc = 0.f;
#pragma unroll
            for (int j = 0; j < 4; ++j) {
                int cb = (cl * 4 + j) * 4 + b2;
                const float* tp = tvw + cb * 20;
                const float4 a0 = *(const float4*)(tp + 0);
                const float4 a1 = *(const float4*)(tp + 4);
                const float4 a2 = *(const float4*)(tp + 8);
                const float4 a3 = *(const float4*)(tp + 12);
                float o = bb;
                o = fmaf(a0.x, wreg[0], o);  o = fmaf(a0.y, wreg[1], o);
                o = fmaf(a0.z, wreg[2], o);  o = fmaf(a0.w, wreg[3], o);
                o = fmaf(a1.x, wreg[4], o);  o = fmaf(a1.y, wreg[5], o);
                o = fmaf(a1.z, wreg[6], o);  o = fmaf(a1.w, wreg[7], o);
                o = fmaf(a2.x, wreg[8], o);  o = fmaf(a2.y, wreg[9], o);
                o = fmaf(a2.z, wreg[10], o); o = fmaf(a2.w, wreg[11], o);
                o = fmaf(a3.x, wreg[12], o); o = fmaf(a3.y, wreg[13], o);
                o = fmaf(a3.z, wreg[14], o); o = fmaf(a3.w, wreg[15], o);
                o = fmaxf(o, 0.f);
                const float2 mrv = *(const float2*)(mr + (wv * 64 + cb) * 2);
                acc += fmaf((o - mrv.x) * mrv.y, gg, bt);
            }
            h3p[((size_t)(C0 + cl) * 4 + b2) * 64 + lane] = f2bf(acc * 0.25f);
        }
    }
}

// ---------------------------------------------------------------------------
// weight fragment prep: pack W3b / (W1b,W2b) into per-lane bf16 MFMA B-frags
__device__ __constant__ const int s12arr[8] = {0, 1, 0, 1, 2, 3, 2, 3};
__device__ __constant__ const int t12arr[8] = {0, 0, 1, 1, 2, 2, 3, 3};

__global__ __launch_bounds__(256) void k_wprep(
    const float* __restrict__ W3b, const float* __restrict__ W1b,
    const float* __restrict__ W2b, uint4* __restrict__ Wfrag3,
    uint4* __restrict__ Wfrag12) {
    int e = blockIdx.x * 256 + threadIdx.x;
    union { uint4 v; bfu u[8]; } p;
    if (e < 1024) {             // coarse3: 16 (s,t) x 64 lanes
        int st = e >> 6, l = e & 63;
        int s = st >> 2, t = st & 3, g = l >> 4, c = l & 15;
#pragma unroll
        for (int j = 0; j < 8; ++j) {
            int k = 32 * s + 8 * g + j;
            int col = 16 * t + c;
            float wv = (k < 64) ? W3b[k * 64 + col] : W3b[4096 + (k - 64) * 64 + col];
            p.u[j] = f2bf(wv);
        }
        Wfrag3[e] = p.v;
    } else if (e < 1536) {      // coarse12: 8 frags x 64 lanes
        int ee = e - 1024;
        int fi = ee >> 6, l = ee & 63;
        int s = s12arr[fi], t = t12arr[fi], g = l >> 4, c = l & 15;
#pragma unroll
        for (int j = 0; j < 8; ++j) {
            int k = 32 * s + 8 * g + j;
            float wv;
            if (t < 2) {
                int col = 16 * t + c;
                wv = (k < 32) ? W1b[k * 32 + col] : W1b[1024 + (k - 32) * 32 + col];
            } else {
                int f2 = 16 * (t - 2) + c;
                int kk = k - 64;
                wv = (kk < 32) ? W2b[kk * 32 + f2] : W2b[1024 + (kk - 32) * 32 + f2];
            }
            p.u[j] = f2bf(wv);
        }
        Wfrag12[ee] = p.v;
    }
}

// ---------------------------------------------------------------------------
// MFMA coarse conv, branch 3. Wave handles 4 c's (16 rows), K=128, N=64.
__global__ __launch_bounds__(256) void k_coarse3m(
    const bfu* __restrict__ h3, const int* __restrict__ idx, const float* __restrict__ w,
    const uint4* __restrict__ Wfrag3, const float* __restrict__ b3b,
    const float* __restrict__ g3b, const float* __restrict__ be3b,
    float* __restrict__ out) {
    __shared__ bfu alds[4][16][136];   // [wave][row][K=128 pad 136]
    int tid = threadIdx.x;
    int lane = tid & 63;
    int wv = tid >> 6;
    int g = lane >> 4, cL = lane & 15;
    int c0 = blockIdx.x * 16 + wv * 4;

    int iv = 0; float wvv = 0.f;
    if (lane < 32) {
        iv = idx[(c0 + (lane >> 3)) * 8 + (lane & 7)];
        wvv = w[(c0 + (lane >> 3)) * 8 + (lane & 7)];
    }
    const ushort4* hb = (const ushort4*)h3;
#pragma unroll
    for (int cl = 0; cl < 4; ++cl) {
        ushort4 v0 = hb[(size_t)(c0 + cl) * 64 + lane];
        float a0 = 0.f, a1 = 0.f, a2 = 0.f, a3 = 0.f;
#pragma unroll
        for (int j = 0; j < 8; ++j) {
            int nj = __shfl(iv, cl * 8 + j);
            float wj = __shfl(wvv, cl * 8 + j);
            ushort4 x = hb[(size_t)nj * 64 + lane];
            a0 = fmaf(wj, bf2f(x.x), a0);
            a1 = fmaf(wj, bf2f(x.y), a1);
            a2 = fmaf(wj, bf2f(x.z), a2);
            a3 = fmaf(wj, bf2f(x.w), a3);
        }
        int r = cl * 4 + g;
        *(ushort4*)&alds[wv][r][4 * cL] = v0;
        ushort4 p;
        p.x = f2bf(a0); p.y = f2bf(a1); p.z = f2bf(a2); p.w = f2bf(a3);
        *(ushort4*)&alds[wv][r][64 + 4 * cL] = p;
    }
    // wave-local LDS (each wave reads only its own region)

    f32x4 acc[4];
#pragma unroll
    for (int t = 0; t < 4; ++t) {
        float bs = b3b[16 * t + cL];
        acc[t] = (f32x4){bs, bs, bs, bs};
    }
    s16x8 af[4];
#pragma unroll
    for (int s = 0; s < 4; ++s)
        af[s] = *(const s16x8*)&alds[wv][cL][32 * s + 8 * g];
#pragma unroll
    for (int s = 0; s < 4; ++s) {
#pragma unroll
        for (int t = 0; t < 4; ++t) {
            s16x8 bf = *(const s16x8*)&Wfrag3[(s * 4 + t) * 64 + lane];
            acc[t] = __builtin_amdgcn_mfma_f32_16x16x32_bf16(af[s], bf, acc[t], 0, 0, 0);
        }
    }

    // relu + LN over 64 features per row (row = 4g+j -> cl=g? no: cl=r>>2, b=r&3)
    float s_[4] = {0.f, 0.f, 0.f, 0.f}, q_[4] = {0.f, 0.f, 0.f, 0.f};
#pragma unroll
    for (int t = 0; t < 4; ++t)
#pragma unroll
        for (int j = 0; j < 4; ++j) {
            float o = fmaxf(acc[t][j], 0.f);
            acc[t][j] = o;
            s_[j] += o; q_[j] = fmaf(o, o, q_[j]);
        }
#pragma unroll
    for (int m = 1; m < 16; m <<= 1)
#pragma unroll
        for (int j = 0; j < 4; ++j) {
            s_[j] += __shfl_xor(s_[j], m, 16);
            q_[j] += __shfl_xor(q_[j], m, 16);
        }
    float mu[4], rs[4];
#pragma unroll
    for (int j = 0; j < 4; ++j) {
        mu[j] = s_[j] * 0.015625f;
        float va = q_[j] * 0.015625f - mu[j] * mu[j];
        rs[j] = rsqrtf(va + 1e-5f);
    }
#pragma unroll
    for (int t = 0; t < 4; ++t) {
        float gg = g3b[16 * t + cL], bt = be3b[16 * t + cL];
#pragma unroll
        for (int j = 0; j < 4; ++j) {
            int r = 4 * g + j;
            int cl = r >> 2, b = r & 3;
            out[((size_t)b * NCC + c0 + cl) * 128 + 64 + 16 * t + cL] =
                fmaf((acc[t][j] - mu[j]) * rs[j], gg, bt);
        }
    }
}

// ---------------------------------------------------------------------------
// MFMA coarse conv, fused branches 1&2. A k-layout [y0b1|y1b1|y0b2|y1b2] (32 ea).
__global__ __launch_bounds__(256) void k_coarse12m(
    const bfu* __restrict__ h12, const int* __restrict__ idx, const float* __restrict__ w,
    const uint4* __restrict__ Wfrag12,
    const float* __restrict__ b1b, const float* __restrict__ g1b, const float* __restrict__ be1b,
    const float* __restrict__ b2b, const float* __restrict__ g2b, const float* __restrict__ be2b,
    float* __restrict__ out) {
    __shared__ bfu alds[4][16][136];
    int tid = threadIdx.x;
    int lane = tid & 63;
    int wv = tid >> 6;
    int g = lane >> 4, cL = lane & 15;
    int c0 = blockIdx.x * 16 + wv * 4;

    int iv = 0; float wvv = 0.f;
    if (lane < 32) {
        iv = idx[(c0 + (lane >> 3)) * 8 + (lane & 7)];
        wvv = w[(c0 + (lane >> 3)) * 8 + (lane & 7)];
    }
    const ushort4* hb = (const ushort4*)h12;
    int k0 = (cL < 8) ? 4 * cL : 32 + 4 * cL;   // y0 dest; y1 at k0+32
#pragma unroll
    for (int cl = 0; cl < 4; ++cl) {
        ushort4 v0 = hb[(size_t)(c0 + cl) * 64 + lane];
        float a0 = 0.f, a1 = 0.f, a2 = 0.f, a3 = 0.f;
#pragma unroll
        for (int j = 0; j < 8; ++j) {
            int nj = __shfl(iv, cl * 8 + j);
            float wj = __shfl(wvv, cl * 8 + j);
            ushort4 x = hb[(size_t)nj * 64 + lane];
            a0 = fmaf(wj, bf2f(x.x), a0);
            a1 = fmaf(wj, bf2f(x.y), a1);
            a2 = fmaf(wj, bf2f(x.z), a2);
            a3 = fmaf(wj, bf2f(x.w), a3);
        }
        int r = cl * 4 + g;
        *(ushort4*)&alds[wv][r][k0] = v0;
        ushort4 p;
        p.x = f2bf(a0); p.y = f2bf(a1); p.z = f2bf(a2); p.w = f2bf(a3);
        *(ushort4*)&alds[wv][r][k0 + 32] = p;
    }

    f32x4 acc[4];
#pragma unroll
    for (int t = 0; t < 4; ++t) {
        float bs = (t < 2) ? b1b[16 * t + cL] : b2b[16 * (t - 2) + cL];
        acc[t] = (f32x4){bs, bs, bs, bs};
    }
    s16x8 af[4];
#pragma unroll
    for (int s = 0; s < 4; ++s)
        af[s] = *(const s16x8*)&alds[wv][cL][32 * s + 8 * g];
#pragma unroll
    for (int fi = 0; fi < 8; ++fi) {
        int s = s12arr[fi], t = t12arr[fi];
        s16x8 bf = *(const s16x8*)&Wfrag12[fi * 64 + lane];
        acc[t] = __builtin_amdgcn_mfma_f32_16x16x32_bf16(af[s], bf, acc[t], 0, 0, 0);
    }

    // relu + per-branch LN (width 32: 2 tiles x 16 lanes)
    float sb[2][4], qb[2][4];
#pragma unroll
    for (int br = 0; br < 2; ++br)
#pragma unroll
        for (int j = 0; j < 4; ++j) { sb[br][j] = 0.f; qb[br][j] = 0.f; }
#pragma unroll
    for (int t = 0; t < 4; ++t) {
        int br = t >> 1;
#pragma unroll
        for (int j = 0; j < 4; ++j) {
            float o = fmaxf(acc[t][j], 0.f);
            acc[t][j] = o;
            sb[br][j] += o; qb[br][j] = fmaf(o, o, qb[br][j]);
        }
    }
#pragma unroll
    for (int m = 1; m < 16; m <<= 1)
#pragma unroll
        for (int br = 0; br < 2; ++br)
#pragma unroll
            for (int j = 0; j < 4; ++j) {
                sb[br][j] += __shfl_xor(sb[br][j], m, 16);
                qb[br][j] += __shfl_xor(qb[br][j], m, 16);
            }
    float mu[2][4], rs[2][4];
#pragma unroll
    for (int br = 0; br < 2; ++br)
#pragma unroll
        for (int j = 0; j < 4; ++j) {
            mu[br][j] = sb[br][j] * 0.03125f;
            float va = qb[br][j] * 0.03125f - mu[br][j] * mu[br][j];
            rs[br][j] = rsqrtf(va + 1e-5f);
        }
#pragma unroll
    for (int t = 0; t < 4; ++t) {
        int br = t >> 1;
        float gg = (t < 2) ? g1b[16 * t + cL] : g2b[16 * (t - 2) + cL];
        float bt = (t < 2) ? be1b[16 * t + cL] : be2b[16 * (t - 2) + cL];
#pragma unroll
        for (int j = 0; j < 4; ++j) {
            int r = 4 * g + j;
            int cl = r >> 2, b = r & 3;
            out[((size_t)b * NCC + c0 + cl) * 128 + 16 * t + cL] =
                fmaf((acc[t][j] - mu[br][j]) * rs[br][j], gg, bt);
        }
    }
}

// ---------------------------------------------------------------------------
extern "C" void kernel_launch(void* const* d_in, const int* in_sizes, int n_in,
                              void* d_out, int out_size, void* d_ws, size_t ws_size,
                              hipStream_t stream) {
    const float* maps = (const float*)d_in[0];
    const float* w8   = (const float*)d_in[1];
    const float* w20  = (const float*)d_in[2];
    const float* w8s  = (const float*)d_in[3];
    const int*   idx8  = (const int*)d_in[4];
    const int*   idx20 = (const int*)d_in[5];
    const int*   idx8s = (const int*)d_in[6];
    const float* W1a = (const float*)d_in[7];
    const float* b1a = (const float*)d_in[8];
    const float* g1a = (const float*)d_in[9];
    const float* be1a = (const float*)d_in[10];
    const float* W1b = (const float*)d_in[11];
    const float* b1b = (const float*)d_in[12];
    const float* g1b = (const float*)d_in[13];
    const float* be1b = (const float*)d_in[14];
    const float* W2a = (const float*)d_in[15];
    const float* b2a = (const float*)d_in[16];
    const float* g2a = (const float*)d_in[17];
    const float* be2a = (const float*)d_in[18];
    const float* W2b = (const float*)d_in[19];
    const float* b2b = (const float*)d_in[20];
    const float* g2b = (const float*)d_in[21];
    const float* be2b = (const float*)d_in[22];
    const float* W3a = (const float*)d_in[23];
    const float* b3a = (const float*)d_in[24];
    const float* g3a = (const float*)d_in[25];
    const float* be3a = (const float*)d_in[26];
    const float* W3b = (const float*)d_in[27];
    const float* b3b = (const float*)d_in[28];
    const float* g3b = (const float*)d_in[29];
    const float* be3b = (const float*)d_in[30];
    float* out = (float*)d_out;

    // workspace (float offsets):
    //   xtH (f16)   @ 0         (786432 floats)
    //   slot[i]     @ 786432*(1+i), i=0..6   (f16 T buffers)
    //   h12p (bf16) @ 12582912  (6291456 floats worth)  [idx8T/w8T overlay]
    //   h3p  (bf16) @ 18874368  (6291456)
    //   idx20T      @ 25165824  (3932160)
    //   w20T        @ 29097984  (3932160)
    //   Wfrag3      @ 33030144  (4096)
    //   Wfrag12     @ 33034240  (2048)
    float* ws = (float*)d_ws;
    uint4* xtH = (uint4*)ws;
    uint4* slot[7];
    for (int i = 0; i < 7; ++i) slot[i] = (uint4*)(ws + (size_t)786432 * (1 + i));
    bfu* h12p = (bfu*)(ws + (size_t)12582912);
    bfu* h3p  = (bfu*)(ws + (size_t)18874368);
    int*   idx8T  = (int*)(ws + 12582912);
    float* w8T    = ws + 12582912 + 1572864;
    int*   idx20T = (int*)(ws + 25165824);
    float* w20T   = ws + 29097984;
    uint4* Wfrag3  = (uint4*)(ws + 33030144);
    uint4* Wfrag12 = (uint4*)(ws + 33034240);

    dim3 blk(256);
    dim3 gN(NPIXF / 256);        // 768
    dim3 gE(NPIXF / 64);         // 3072
    dim3 gC(NCC / 16);           // 3072 (MFMA coarse: 16 c per block)

    k_wprep<<<6, blk, 0, stream>>>(W3b, W1b, W2b, Wfrag3, Wfrag12);
    k_tiw<8><<<gN, blk, 0, stream>>>(idx8, w8, idx8T, w8T);
    k_tiw<20><<<gN, blk, 0, stream>>>(idx20, w20, idx20T, w20T);
    k_transposeH<<<gN, blk, 0, stream>>>(maps, xtH);

    // 8-neighbor chain: T1..T5
    k_lapH<8, true><<<gN, blk, 0, stream>>>(xtH, xtH, slot[0], idx8T, w8T);
    k_lapH<8, false><<<gN, blk, 0, stream>>>(slot[0], xtH, slot[1], idx8T, w8T);
    k_lapH<8, false><<<gN, blk, 0, stream>>>(slot[1], slot[0], slot[2], idx8T, w8T);
    k_lapH<8, false><<<gN, blk, 0, stream>>>(slot[2], slot[1], slot[3], idx8T, w8T);
    k_lapH<8, false><<<gN, blk, 0, stream>>>(slot[3], slot[2], slot[4], idx8T, w8T);

    k_epiA<<<gE, blk, 0, stream>>>((const unsigned*)xtH, (const unsigned*)slot[0],
                                   (const unsigned*)slot[1], (const unsigned*)slot[2],
                                   (const unsigned*)slot[3], (const unsigned*)slot[4],
                                   W1a, b1a, g1a, be1a, W2a, b2a, g2a, be2a, h12p);

    // 20-neighbor chain: T1..T7
    k_lapH<20, true><<<gN, blk, 0, stream>>>(xtH, xtH, slot[0], idx20T, w20T);
    k_lapH<20, false><<<gN, blk, 0, stream>>>(slot[0], xtH, slot[1], idx20T, w20T);
    k_lapH<20, false><<<gN, blk, 0, stream>>>(slot[1], slot[0], slot[2], idx20T, w20T);
    k_lapH<20, false><<<gN, blk, 0, stream>>>(slot[2], slot[1], slot[3], idx20T, w20T);
    k_lapH<20, false><<<gN, blk, 0, stream>>>(slot[3], slot[2], slot[4], idx20T, w20T);
    k_lapH<20, false><<<gN, blk, 0, stream>>>(slot[4], slot[3], slot[5], idx20T, w20T);
    k_lapH<20, false><<<gN, blk, 0, stream>>>(slot[5], slot[4], slot[6], idx20T, w20T);

    k_epiB<<<gE, blk, 0, stream>>>((const unsigned*)xtH, (const unsigned*)slot[0],
                                   (const unsigned*)slot[1], (const unsigned*)slot[2],
                                   (const unsigned*)slot[3], (const unsigned*)slot[4],
                                   (const unsigned*)slot[5], (const unsigned*)slot[6],
                                   W3a, b3a, g3a, be3a, h3p);

    // MFMA coarse convs -> concatenated output [B][NCC][128]
    k_coarse12m<<<gC, blk, 0, stream>>>(h12p, idx8s, w8s, Wfrag12,
                                        b1b, g1b, be1b, b2b, g2b, be2b, out);
    k_coarse3m<<<gC, blk, 0, stream>>>(h3p, idx8s, w8s, Wfrag3, b3b, g3b, be3b, out);
}

// Round 8
// 583.564 us; speedup vs baseline: 2.2028x; 1.0228x over previous
//
#include <hip/hip_runtime.h>
#include <math.h>

#define NPIXF 196608   // fine nodes
#define NCC   49152    // coarse nodes
// fine T layout: [N][8] _Float16 (16B per node; b major, ch minor)
// coarse h layout: [c][b][f] bf16 (c-major: one wave gathers a full node)

typedef unsigned short bfu;
typedef __attribute__((ext_vector_type(8))) short s16x8;
typedef __attribute__((ext_vector_type(4))) float f32x4;

__device__ inline bfu f2bf(float x) {
    union { float f; unsigned u; } v; v.f = x;
    unsigned r = v.u + 0x7fff + ((v.u >> 16) & 1);   // RNE
    return (bfu)(r >> 16);
}
__device__ inline float bf2f(bfu b) {
    union { unsigned u; float f; } v; v.u = ((unsigned)b) << 16;
    return v.f;
}
__device__ inline float h2f(unsigned short h) {
    _Float16 x; __builtin_memcpy(&x, &h, 2); return (float)x;
}
__device__ inline unsigned short f2h(float f) {
    _Float16 x = (_Float16)f; unsigned short r; __builtin_memcpy(&r, &x, 2); return r;
}
union HPack { uint4 v; unsigned short u[8]; };

// ---------------------------------------------------------------------------
// transpose idx/w [N][NN] -> [NN][N]
template <int NN>
__global__ __launch_bounds__(256) void k_tiw(const int* __restrict__ idx,
                                             const float* __restrict__ w,
                                             int* __restrict__ idxT,
                                             float* __restrict__ wT) {
    int n = blockIdx.x * 256 + threadIdx.x;
    if (n >= NPIXF) return;
#pragma unroll
    for (int j = 0; j < NN; ++j) {
        idxT[j * NPIXF + n] = idx[(size_t)n * NN + j];
        wT[j * NPIXF + n]   = w[(size_t)n * NN + j];
    }
}

// transpose maps [B][N][2] fp32 -> xtH [N][8] f16
__global__ __launch_bounds__(256) void k_transposeH(const float* __restrict__ maps,
                                                    uint4* __restrict__ xtH) {
    int n = blockIdx.x * 256 + threadIdx.x;
    if (n >= NPIXF) return;
    const float2* m2 = (const float2*)maps;
    HPack p;
#pragma unroll
    for (int b = 0; b < 4; ++b) {
        float2 v = m2[(size_t)b * NPIXF + n];
        p.u[2 * b]     = f2h(v.x);
        p.u[2 * b + 1] = f2h(v.y);
    }
    xtH[n] = p.v;
}

// ---------------------------------------------------------------------------
// Chebyshev step, f16 payload, 1 thread/node. FIRST: dst=lap(src) else 2*lap-src2
template <int NN, bool FIRST>
__global__ __launch_bounds__(256) void k_lapH(const uint4* __restrict__ src,
                                              const uint4* __restrict__ src2,
                                              uint4* __restrict__ dst,
                                              const int* __restrict__ idxT,
                                              const float* __restrict__ wT) {
    int n = blockIdx.x * 256 + threadIdx.x;
    if (n >= NPIXF) return;
    int nj[NN]; float wj[NN];
#pragma unroll
    for (int j = 0; j < NN; ++j) {
        nj[j] = idxT[j * NPIXF + n];
        wj[j] = wT[j * NPIXF + n];
    }
    float a[8] = {0.f, 0.f, 0.f, 0.f, 0.f, 0.f, 0.f, 0.f};
#pragma unroll
    for (int j = 0; j < NN; ++j) {
        HPack x; x.v = src[nj[j]];
#pragma unroll
        for (int e = 0; e < 8; ++e) a[e] = fmaf(wj[j], h2f(x.u[e]), a[e]);
    }
    HPack o;
    if (FIRST) {
#pragma unroll
        for (int e = 0; e < 8; ++e) o.u[e] = f2h(a[e]);
    } else {
        HPack q; q.v = src2[n];
#pragma unroll
        for (int e = 0; e < 8; ++e) o.u[e] = f2h(2.f * a[e] - h2f(q.u[e]));
    }
    dst[n] = o.v;
}

// ---------------------------------------------------------------------------
// weight fragment prep: pack coarse-conv and epilogue weights as bf16 B-frags
__device__ __constant__ const int s12arr[8] = {0, 1, 0, 1, 2, 3, 2, 3};
__device__ __constant__ const int t12arr[8] = {0, 0, 1, 1, 2, 2, 3, 3};

__global__ __launch_bounds__(256) void k_wprep(
    const float* __restrict__ W3b, const float* __restrict__ W1b,
    const float* __restrict__ W2b, const float* __restrict__ W3a,
    const float* __restrict__ W1a, const float* __restrict__ W2a,
    uint4* __restrict__ Wfrag3, uint4* __restrict__ Wfrag12,
    uint4* __restrict__ WfragE3, uint4* __restrict__ WfragE12) {
    int e = blockIdx.x * 256 + threadIdx.x;
    union { uint4 v; bfu u[8]; } p;
    if (e < 1024) {             // coarse3: 16 (s,t) x 64 lanes
        int st = e >> 6, l = e & 63;
        int s = st >> 2, t = st & 3, g = l >> 4, c = l & 15;
#pragma unroll
        for (int j = 0; j < 8; ++j) {
            int k = 32 * s + 8 * g + j;
            int col = 16 * t + c;
            float wv = (k < 64) ? W3b[k * 64 + col] : W3b[4096 + (k - 64) * 64 + col];
            p.u[j] = f2bf(wv);
        }
        Wfrag3[e] = p.v;
    } else if (e < 1536) {      // coarse12: 8 frags x 64 lanes
        int ee = e - 1024;
        int fi = ee >> 6, l = ee & 63;
        int s = s12arr[fi], t = t12arr[fi], g = l >> 4, c = l & 15;
#pragma unroll
        for (int j = 0; j < 8; ++j) {
            int k = 32 * s + 8 * g + j;
            float wv;
            if (t < 2) {
                int col = 16 * t + c;
                wv = (k < 32) ? W1b[k * 32 + col] : W1b[1024 + (k - 32) * 32 + col];
            } else {
                int f2 = 16 * (t - 2) + c;
                int kk = k - 64;
                wv = (kk < 32) ? W2b[kk * 32 + f2] : W2b[1024 + (kk - 32) * 32 + f2];
            }
            p.u[j] = f2bf(wv);
        }
        Wfrag12[ee] = p.v;
    } else if (e < 1792) {      // epilogue branch3: 4 tiles x 64 lanes, K=32 (16 real)
        int ee = e - 1536;
        int t = ee >> 6, l = ee & 63;
        int g = l >> 4, c = l & 15;
#pragma unroll
        for (int j = 0; j < 8; ++j) {
            int k = 8 * g + j;
            float wv = (k < 16) ? W3a[k * 64 + 16 * t + c] : 0.f;
            p.u[j] = f2bf(wv);
        }
        WfragE3[ee] = p.v;
    } else if (e < 2048) {      // epilogue br1&2: 4 tiles x 64 lanes
        int ee = e - 1792;
        int t = ee >> 6, l = ee & 63;
        int g = l >> 4, c = l & 15;
        int col = 16 * t + c;
#pragma unroll
        for (int j = 0; j < 8; ++j) {
            int k = 8 * g + j;
            float wv = 0.f;
            if (col < 32) { if (k < 8)  wv = W1a[k * 32 + col]; }
            else          { if (k < 12) wv = W2a[k * 32 + (col - 32)]; }
            p.u[j] = f2bf(wv);
        }
        WfragE12[ee] = p.v;
    }
}

// ---------------------------------------------------------------------------
// MFMA epilogue branches 1&2: per wave one coarse node c.
// A[16 rows=(4jf+b)][K=32 (12 real)] bf16 from T0..T5; B = WfragE12 (4 col tiles).
// relu -> per-branch LN (width 32) -> pool over jf -> bf16 h12[c][b][64].
__global__ __launch_bounds__(256) void k_epiAm(
    const unsigned* __restrict__ t0, const unsigned* __restrict__ t1,
    const unsigned* __restrict__ t2, const unsigned* __restrict__ t3,
    const unsigned* __restrict__ t4, const unsigned* __restrict__ t5,
    const uint4* __restrict__ WfragE12,
    const float* __restrict__ b1a, const float* __restrict__ g1a,
    const float* __restrict__ be1a,
    const float* __restrict__ b2a, const float* __restrict__ g2a,
    const float* __restrict__ be2a,
    bfu* __restrict__ h12p) {
    __shared__ bfu alds[4][16][34];   // [wave][row][K=32 pad34]
    int tid = threadIdx.x;
    int lane = tid & 63;
    int wv = tid >> 6;
    int c = blockIdx.x * 4 + wv;
    int r = lane & 15, q = lane >> 4;

    // stage A: chunk q covers k = 8q..8q+7 (t = 4q..4q+3); q>=2 -> zeros
    union { uint4 v; bfu u[8]; } pk;
    if (q == 0) {
        int uidx = 16 * c + r;
        unsigned v0 = t0[uidx], v1 = t1[uidx], v2 = t2[uidx], v3 = t3[uidx];
        pk.u[0] = f2bf(h2f((unsigned short)(v0 & 0xffff)));
        pk.u[1] = f2bf(h2f((unsigned short)(v0 >> 16)));
        pk.u[2] = f2bf(h2f((unsigned short)(v1 & 0xffff)));
        pk.u[3] = f2bf(h2f((unsigned short)(v1 >> 16)));
        pk.u[4] = f2bf(h2f((unsigned short)(v2 & 0xffff)));
        pk.u[5] = f2bf(h2f((unsigned short)(v2 >> 16)));
        pk.u[6] = f2bf(h2f((unsigned short)(v3 & 0xffff)));
        pk.u[7] = f2bf(h2f((unsigned short)(v3 >> 16)));
    } else if (q == 1) {
        int uidx = 16 * c + r;
        unsigned v4 = t4[uidx], v5 = t5[uidx];
        pk.u[0] = f2bf(h2f((unsigned short)(v4 & 0xffff)));
        pk.u[1] = f2bf(h2f((unsigned short)(v4 >> 16)));
        pk.u[2] = f2bf(h2f((unsigned short)(v5 & 0xffff)));
        pk.u[3] = f2bf(h2f((unsigned short)(v5 >> 16)));
        pk.u[4] = 0; pk.u[5] = 0; pk.u[6] = 0; pk.u[7] = 0;
    } else {
        pk.u[0] = 0; pk.u[1] = 0; pk.u[2] = 0; pk.u[3] = 0;
        pk.u[4] = 0; pk.u[5] = 0; pk.u[6] = 0; pk.u[7] = 0;
    }
    *(uint4*)&alds[wv][r][8 * q] = pk.v;
    // wave-local LDS: same wave wrote what it reads.

    int cL = lane & 15, g = lane >> 4;
    f32x4 acc[4];
#pragma unroll
    for (int t = 0; t < 4; ++t) {
        int f = 16 * t + cL;
        float bs = (t < 2) ? b1a[f] : b2a[f - 32];
        acc[t] = (f32x4){bs, bs, bs, bs};
    }
    s16x8 af = *(const s16x8*)&alds[wv][cL][8 * g];
#pragma unroll
    for (int t = 0; t < 4; ++t) {
        s16x8 bf = *(const s16x8*)&WfragE12[t * 64 + lane];
        acc[t] = __builtin_amdgcn_mfma_f32_16x16x32_bf16(af, bf, acc[t], 0, 0, 0);
    }

    // relu + per-branch LN (rows: jf = g, b = reg)
    float sb[2][4], qb[2][4];
#pragma unroll
    for (int br = 0; br < 2; ++br)
#pragma unroll
        for (int j = 0; j < 4; ++j) { sb[br][j] = 0.f; qb[br][j] = 0.f; }
#pragma unroll
    for (int t = 0; t < 4; ++t) {
        int br = t >> 1;
#pragma unroll
        for (int j = 0; j < 4; ++j) {
            float o = fmaxf(acc[t][j], 0.f);
            acc[t][j] = o;
            sb[br][j] += o; qb[br][j] = fmaf(o, o, qb[br][j]);
        }
    }
#pragma unroll
    for (int m = 1; m < 16; m <<= 1)
#pragma unroll
        for (int br = 0; br < 2; ++br)
#pragma unroll
            for (int j = 0; j < 4; ++j) {
                sb[br][j] += __shfl_xor(sb[br][j], m, 16);
                qb[br][j] += __shfl_xor(qb[br][j], m, 16);
            }
    // normalize + gamma/beta, then pool over jf (cross-group) and store
#pragma unroll
    for (int t = 0; t < 4; ++t) {
        int br = t >> 1;
        int f = 16 * t + cL;
        float gg = (t < 2) ? g1a[f] : g2a[f - 32];
        float bt = (t < 2) ? be1a[f] : be2a[f - 32];
#pragma unroll
        for (int j = 0; j < 4; ++j) {
            float mu = sb[br][j] * 0.03125f;
            float va = qb[br][j] * 0.03125f - mu * mu;
            float v = fmaf((acc[t][j] - mu) * rsqrtf(va + 1e-5f), gg, bt);
            v += __shfl_xor(v, 16, 64);
            v += __shfl_xor(v, 32, 64);
            if (g == t)
                h12p[((size_t)c * 4 + j) * 64 + f] = f2bf(v * 0.25f);
        }
    }
}

// ---------------------------------------------------------------------------
// MFMA epilogue branch 3: per wave one coarse node; K=32 (16 real), LN width 64.
__global__ __launch_bounds__(256) void k_epiBm(
    const unsigned* __restrict__ t0, const unsigned* __restrict__ t1,
    const unsigned* __restrict__ t2, const unsigned* __restrict__ t3,
    const unsigned* __restrict__ t4, const unsigned* __restrict__ t5,
    const unsigned* __restrict__ t6, const unsigned* __restrict__ t7,
    const uint4* __restrict__ WfragE3,
    const float* __restrict__ b3a, const float* __restrict__ g3a,
    const float* __restrict__ be3a,
    bfu* __restrict__ h3p) {
    __shared__ bfu alds[4][16][34];
    int tid = threadIdx.x;
    int lane = tid & 63;
    int wv = tid >> 6;
    int c = blockIdx.x * 4 + wv;
    int r = lane & 15, q = lane >> 4;

    union { uint4 v; bfu u[8]; } pk;
    if (q < 2) {
        int uidx = 16 * c + r;
        unsigned v0, v1, v2, v3;
        if (q == 0) { v0 = t0[uidx]; v1 = t1[uidx]; v2 = t2[uidx]; v3 = t3[uidx]; }
        else        { v0 = t4[uidx]; v1 = t5[uidx]; v2 = t6[uidx]; v3 = t7[uidx]; }
        pk.u[0] = f2bf(h2f((unsigned short)(v0 & 0xffff)));
        pk.u[1] = f2bf(h2f((unsigned short)(v0 >> 16)));
        pk.u[2] = f2bf(h2f((unsigned short)(v1 & 0xffff)));
        pk.u[3] = f2bf(h2f((unsigned short)(v1 >> 16)));
        pk.u[4] = f2bf(h2f((unsigned short)(v2 & 0xffff)));
        pk.u[5] = f2bf(h2f((unsigned short)(v2 >> 16)));
        pk.u[6] = f2bf(h2f((unsigned short)(v3 & 0xffff)));
        pk.u[7] = f2bf(h2f((unsigned short)(v3 >> 16)));
    } else {
        pk.u[0] = 0; pk.u[1] = 0; pk.u[2] = 0; pk.u[3] = 0;
        pk.u[4] = 0; pk.u[5] = 0; pk.u[6] = 0; pk.u[7] = 0;
    }
    *(uint4*)&alds[wv][r][8 * q] = pk.v;

    int cL = lane & 15, g = lane >> 4;
    f32x4 acc[4];
#pragma unroll
    for (int t = 0; t < 4; ++t) {
        float bs = b3a[16 * t + cL];
        acc[t] = (f32x4){bs, bs, bs, bs};
    }
    s16x8 af = *(const s16x8*)&alds[wv][cL][8 * g];
#pragma unroll
    for (int t = 0; t < 4; ++t) {
        s16x8 bf = *(const s16x8*)&WfragE3[t * 64 + lane];
        acc[t] = __builtin_amdgcn_mfma_f32_16x16x32_bf16(af, bf, acc[t], 0, 0, 0);
    }

    float s_[4] = {0.f, 0.f, 0.f, 0.f}, q_[4] = {0.f, 0.f, 0.f, 0.f};
#pragma unroll
    for (int t = 0; t < 4; ++t)
#pragma unroll
        for (int j = 0; j < 4; ++j) {
            float o = fmaxf(acc[t][j], 0.f);
            acc[t][j] = o;
            s_[j] += o; q_[j] = fmaf(o, o, q_[j]);
        }
#pragma unroll
    for (int m = 1; m < 16; m <<= 1)
#pragma unroll
        for (int j = 0; j < 4; ++j) {
            s_[j] += __shfl_xor(s_[j], m, 16);
            q_[j] += __shfl_xor(q_[j], m, 16);
        }
#pragma unroll
    for (int t = 0; t < 4; ++t) {
        int f = 16 * t + cL;
        float gg = g3a[f], bt = be3a[f];
#pragma unroll
        for (int j = 0; j < 4; ++j) {
            float mu = s_[j] * 0.015625f;
            float va = q_[j] * 0.015625f - mu * mu;
            float v = fmaf((acc[t][j] - mu) * rsqrtf(va + 1e-5f), gg, bt);
            v += __shfl_xor(v, 16, 64);
            v += __shfl_xor(v, 32, 64);
            if (g == t)
                h3p[((size_t)c * 4 + j) * 64 + f] = f2bf(v * 0.25f);
        }
    }
}

// ---------------------------------------------------------------------------
// MFMA coarse conv, branch 3. Wave handles 4 c's (16 rows), K=128, N=64.
__global__ __launch_bounds__(256) void k_coarse3m(
    const bfu* __restrict__ h3, const int* __restrict__ idx, const float* __restrict__ w,
    const uint4* __restrict__ Wfrag3, const float* __restrict__ b3b,
    const float* __restrict__ g3b, const float* __restrict__ be3b,
    float* __restrict__ out) {
    __shared__ bfu alds[4][16][136];   // [wave][row][K=128 pad 136]
    int tid = threadIdx.x;
    int lane = tid & 63;
    int wv = tid >> 6;
    int g = lane >> 4, cL = lane & 15;
    int c0 = blockIdx.x * 16 + wv * 4;

    int iv = 0; float wvv = 0.f;
    if (lane < 32) {
        iv = idx[(c0 + (lane >> 3)) * 8 + (lane & 7)];
        wvv = w[(c0 + (lane >> 3)) * 8 + (lane & 7)];
    }
    const ushort4* hb = (const ushort4*)h3;
#pragma unroll
    for (int cl = 0; cl < 4; ++cl) {
        ushort4 v0 = hb[(size_t)(c0 + cl) * 64 + lane];
        float a0 = 0.f, a1 = 0.f, a2 = 0.f, a3 = 0.f;
#pragma unroll
        for (int j = 0; j < 8; ++j) {
            int nj = __shfl(iv, cl * 8 + j);
            float wj = __shfl(wvv, cl * 8 + j);
            ushort4 x = hb[(size_t)nj * 64 + lane];
            a0 = fmaf(wj, bf2f(x.x), a0);
            a1 = fmaf(wj, bf2f(x.y), a1);
            a2 = fmaf(wj, bf2f(x.z), a2);
            a3 = fmaf(wj, bf2f(x.w), a3);
        }
        int r = cl * 4 + g;
        *(ushort4*)&alds[wv][r][4 * cL] = v0;
        ushort4 p;
        p.x = f2bf(a0); p.y = f2bf(a1); p.z = f2bf(a2); p.w = f2bf(a3);
        *(ushort4*)&alds[wv][r][64 + 4 * cL] = p;
    }

    f32x4 acc[4];
#pragma unroll
    for (int t = 0; t < 4; ++t) {
        float bs = b3b[16 * t + cL];
        acc[t] = (f32x4){bs, bs, bs, bs};
    }
    s16x8 af[4];
#pragma unroll
    for (int s = 0; s < 4; ++s)
        af[s] = *(const s16x8*)&alds[wv][cL][32 * s + 8 * g];
#pragma unroll
    for (int s = 0; s < 4; ++s) {
#pragma unroll
        for (int t = 0; t < 4; ++t) {
            s16x8 bf = *(const s16x8*)&Wfrag3[(s * 4 + t) * 64 + lane];
            acc[t] = __builtin_amdgcn_mfma_f32_16x16x32_bf16(af[s], bf, acc[t], 0, 0, 0);
        }
    }

    float s_[4] = {0.f, 0.f, 0.f, 0.f}, q_[4] = {0.f, 0.f, 0.f, 0.f};
#pragma unroll
    for (int t = 0; t < 4; ++t)
#pragma unroll
        for (int j = 0; j < 4; ++j) {
            float o = fmaxf(acc[t][j], 0.f);
            acc[t][j] = o;
            s_[j] += o; q_[j] = fmaf(o, o, q_[j]);
        }
#pragma unroll
    for (int m = 1; m < 16; m <<= 1)
#pragma unroll
        for (int j = 0; j < 4; ++j) {
            s_[j] += __shfl_xor(s_[j], m, 16);
            q_[j] += __shfl_xor(q_[j], m, 16);
        }
    float mu[4], rs[4];
#pragma unroll
    for (int j = 0; j < 4; ++j) {
        mu[j] = s_[j] * 0.015625f;
        float va = q_[j] * 0.015625f - mu[j] * mu[j];
        rs[j] = rsqrtf(va + 1e-5f);
    }
#pragma unroll
    for (int t = 0; t < 4; ++t) {
        float gg = g3b[16 * t + cL], bt = be3b[16 * t + cL];
#pragma unroll
        for (int j = 0; j < 4; ++j) {
            int r = 4 * g + j;
            int cl = r >> 2, b = r & 3;
            out[((size_t)b * NCC + c0 + cl) * 128 + 64 + 16 * t + cL] =
                fmaf((acc[t][j] - mu[j]) * rs[j], gg, bt);
        }
    }
}

// ---------------------------------------------------------------------------
// MFMA coarse conv, fused branches 1&2. A k-layout [y0b1|y1b1|y0b2|y1b2] (32 ea).
__global__ __launch_bounds__(256) void k_coarse12m(
    const bfu* __restrict__ h12, const int* __restrict__ idx, const float* __restrict__ w,
    const uint4* __restrict__ Wfrag12,
    const float* __restrict__ b1b, const float* __restrict__ g1b, const float* __restrict__ be1b,
    const float* __restrict__ b2b, const float* __restrict__ g2b, const float* __restrict__ be2b,
    float* __restrict__ out) {
    __shared__ bfu alds[4][16][136];
    int tid = threadIdx.x;
    int lane = tid & 63;
    int wv = tid >> 6;
    int g = lane >> 4, cL = lane & 15;
    int c0 = blockIdx.x * 16 + wv * 4;

    int iv = 0; float wvv = 0.f;
    if (lane < 32) {
        iv = idx[(c0 + (lane >> 3)) * 8 + (lane & 7)];
        wvv = w[(c0 + (lane >> 3)) * 8 + (lane & 7)];
    }
    const ushort4* hb = (const ushort4*)h12;
    int k0 = (cL < 8) ? 4 * cL : 32 + 4 * cL;   // y0 dest; y1 at k0+32
#pragma unroll
    for (int cl = 0; cl < 4; ++cl) {
        ushort4 v0 = hb[(size_t)(c0 + cl) * 64 + lane];
        float a0 = 0.f, a1 = 0.f, a2 = 0.f, a3 = 0.f;
#pragma unroll
        for (int j = 0; j < 8; ++j) {
            int nj = __shfl(iv, cl * 8 + j);
            float wj = __shfl(wvv, cl * 8 + j);
            ushort4 x = hb[(size_t)nj * 64 + lane];
            a0 = fmaf(wj, bf2f(x.x), a0);
            a1 = fmaf(wj, bf2f(x.y), a1);
            a2 = fmaf(wj, bf2f(x.z), a2);
            a3 = fmaf(wj, bf2f(x.w), a3);
        }
        int r = cl * 4 + g;
        *(ushort4*)&alds[wv][r][k0] = v0;
        ushort4 p;
        p.x = f2bf(a0); p.y = f2bf(a1); p.z = f2bf(a2); p.w = f2bf(a3);
        *(ushort4*)&alds[wv][r][k0 + 32] = p;
    }

    f32x4 acc[4];
#pragma unroll
    for (int t = 0; t < 4; ++t) {
        float bs = (t < 2) ? b1b[16 * t + cL] : b2b[16 * (t - 2) + cL];
        acc[t] = (f32x4){bs, bs, bs, bs};
    }
    s16x8 af[4];
#pragma unroll
    for (int s = 0; s < 4; ++s)
        af[s] = *(const s16x8*)&alds[wv][cL][32 * s + 8 * g];
#pragma unroll
    for (int fi = 0; fi < 8; ++fi) {
        int s = s12arr[fi], t = t12arr[fi];
        s16x8 bf = *(const s16x8*)&Wfrag12[fi * 64 + lane];
        acc[t] = __builtin_amdgcn_mfma_f32_16x16x32_bf16(af[s], bf, acc[t], 0, 0, 0);
    }

    float sb[2][4], qb[2][4];
#pragma unroll
    for (int br = 0; br < 2; ++br)
#pragma unroll
        for (int j = 0; j < 4; ++j) { sb[br][j] = 0.f; qb[br][j] = 0.f; }
#pragma unroll
    for (int t = 0; t < 4; ++t) {
        int br = t >> 1;
#pragma unroll
        for (int j = 0; j < 4; ++j) {
            float o = fmaxf(acc[t][j], 0.f);
            acc[t][j] = o;
            sb[br][j] += o; qb[br][j] = fmaf(o, o, qb[br][j]);
        }
    }
#pragma unroll
    for (int m = 1; m < 16; m <<= 1)
#pragma unroll
        for (int br = 0; br < 2; ++br)
#pragma unroll
            for (int j = 0; j < 4; ++j) {
                sb[br][j] += __shfl_xor(sb[br][j], m, 16);
                qb[br][j] += __shfl_xor(qb[br][j], m, 16);
            }
    float mu[2][4], rs[2][4];
#pragma unroll
    for (int br = 0; br < 2; ++br)
#pragma unroll
        for (int j = 0; j < 4; ++j) {
            mu[br][j] = sb[br][j] * 0.03125f;
            float va = qb[br][j] * 0.03125f - mu[br][j] * mu[br][j];
            rs[br][j] = rsqrtf(va + 1e-5f);
        }
#pragma unroll
    for (int t = 0; t < 4; ++t) {
        int br = t >> 1;
        float gg = (t < 2) ? g1b[16 * t + cL] : g2b[16 * (t - 2) + cL];
        float bt = (t < 2) ? be1b[16 * t + cL] : be2b[16 * (t - 2) + cL];
#pragma unroll
        for (int j = 0; j < 4; ++j) {
            int r = 4 * g + j;
            int cl = r >> 2, b = r & 3;
            out[((size_t)b * NCC + c0 + cl) * 128 + 16 * t + cL] =
                fmaf((acc[t][j] - mu[br][j]) * rs[br][j], gg, bt);
        }
    }
}

// ---------------------------------------------------------------------------
extern "C" void kernel_launch(void* const* d_in, const int* in_sizes, int n_in,
                              void* d_out, int out_size, void* d_ws, size_t ws_size,
                              hipStream_t stream) {
    const float* maps = (const float*)d_in[0];
    const float* w8   = (const float*)d_in[1];
    const float* w20  = (const float*)d_in[2];
    const float* w8s  = (const float*)d_in[3];
    const int*   idx8  = (const int*)d_in[4];
    const int*   idx20 = (const int*)d_in[5];
    const int*   idx8s = (const int*)d_in[6];
    const float* W1a = (const float*)d_in[7];
    const float* b1a = (const float*)d_in[8];
    const float* g1a = (const float*)d_in[9];
    const float* be1a = (const float*)d_in[10];
    const float* W1b = (const float*)d_in[11];
    const float* b1b = (const float*)d_in[12];
    const float* g1b = (const float*)d_in[13];
    const float* be1b = (const float*)d_in[14];
    const float* W2a = (const float*)d_in[15];
    const float* b2a = (const float*)d_in[16];
    const float* g2a = (const float*)d_in[17];
    const float* be2a = (const float*)d_in[18];
    const float* W2b = (const float*)d_in[19];
    const float* b2b = (const float*)d_in[20];
    const float* g2b = (const float*)d_in[21];
    const float* be2b = (const float*)d_in[22];
    const float* W3a = (const float*)d_in[23];
    const float* b3a = (const float*)d_in[24];
    const float* g3a = (const float*)d_in[25];
    const float* be3a = (const float*)d_in[26];
    const float* W3b = (const float*)d_in[27];
    const float* b3b = (const float*)d_in[28];
    const float* g3b = (const float*)d_in[29];
    const float* be3b = (const float*)d_in[30];
    float* out = (float*)d_out;

    // workspace (float offsets):
    //   xtH (f16)   @ 0         (786432 floats)
    //   slot[i]     @ 786432*(1+i), i=0..6   (f16 T buffers)
    //   h12p (bf16) @ 12582912  [idx8T/w8T overlay]
    //   h3p  (bf16) @ 18874368
    //   idx20T      @ 25165824
    //   w20T        @ 29097984
    //   Wfrag3      @ 33030144 (4096), Wfrag12 @ 33034240 (2048)
    //   WfragE3     @ 33036288 (1024), WfragE12 @ 33037312 (1024)
    float* ws = (float*)d_ws;
    uint4* xtH = (uint4*)ws;
    uint4* slot[7];
    for (int i = 0; i < 7; ++i) slot[i] = (uint4*)(ws + (size_t)786432 * (1 + i));
    bfu* h12p = (bfu*)(ws + (size_t)12582912);
    bfu* h3p  = (bfu*)(ws + (size_t)18874368);
    int*   idx8T  = (int*)(ws + 12582912);
    float* w8T    = ws + 12582912 + 1572864;
    int*   idx20T = (int*)(ws + 25165824);
    float* w20T   = ws + 29097984;
    uint4* Wfrag3   = (uint4*)(ws + 33030144);
    uint4* Wfrag12  = (uint4*)(ws + 33034240);
    uint4* WfragE3  = (uint4*)(ws + 33036288);
    uint4* WfragE12 = (uint4*)(ws + 33037312);

    dim3 blk(256);
    dim3 gN(NPIXF / 256);        // 768
    dim3 gEm(NCC / 4);           // 12288 (MFMA epilogue: 1 wave/coarse node)
    dim3 gC(NCC / 16);           // 3072 (MFMA coarse: 16 c per block)

    k_wprep<<<8, blk, 0, stream>>>(W3b, W1b, W2b, W3a, W1a, W2a,
                                   Wfrag3, Wfrag12, WfragE3, WfragE12);
    k_tiw<8><<<gN, blk, 0, stream>>>(idx8, w8, idx8T, w8T);
    k_tiw<20><<<gN, blk, 0, stream>>>(idx20, w20, idx20T, w20T);
    k_transposeH<<<gN, blk, 0, stream>>>(maps, xtH);

    // 8-neighbor chain: T1..T5
    k_lapH<8, true><<<gN, blk, 0, stream>>>(xtH, xtH, slot[0], idx8T, w8T);
    k_lapH<8, false><<<gN, blk, 0, stream>>>(slot[0], xtH, slot[1], idx8T, w8T);
    k_lapH<8, false><<<gN, blk, 0, stream>>>(slot[1], slot[0], slot[2], idx8T, w8T);
    k_lapH<8, false><<<gN, blk, 0, stream>>>(slot[2], slot[1], slot[3], idx8T, w8T);
    k_lapH<8, false><<<gN, blk, 0, stream>>>(slot[3], slot[2], slot[4], idx8T, w8T);

    k_epiAm<<<gEm, blk, 0, stream>>>((const unsigned*)xtH, (const unsigned*)slot[0],
                                     (const unsigned*)slot[1], (const unsigned*)slot[2],
                                     (const unsigned*)slot[3], (const unsigned*)slot[4],
                                     WfragE12, b1a, g1a, be1a, b2a, g2a, be2a, h12p);

    // 20-neighbor chain: T1..T7
    k_lapH<20, true><<<gN, blk, 0, stream>>>(xtH, xtH, slot[0], idx20T, w20T);
    k_lapH<20, false><<<gN, blk, 0, stream>>>(slot[0], xtH, slot[1], idx20T, w20T);
    k_lapH<20, false><<<gN, blk, 0, stream>>>(slot[1], slot[0], slot[2], idx20T, w20T);
    k_lapH<20, false><<<gN, blk, 0, stream>>>(slot[2], slot[1], slot[3], idx20T, w20T);
    k_lapH<20, false><<<gN, blk, 0, stream>>>(slot[3], slot[2], slot[4], idx20T, w20T);
    k_lapH<20, false><<<gN, blk, 0, stream>>>(slot[4], slot[3], slot[5], idx20T, w20T);
    k_lapH<20, false><<<gN, blk, 0, stream>>>(slot[5], slot[4], slot[6], idx20T, w20T);

    k_epiBm<<<gEm, blk, 0, stream>>>((const unsigned*)xtH, (const unsigned*)slot[0],
                                     (const unsigned*)slot[1], (const unsigned*)slot[2],
                                     (const unsigned*)slot[3], (const unsigned*)slot[4],
                                     (const unsigned*)slot[5], (const unsigned*)slot[6],
                                     WfragE3, b3a, g3a, be3a, h3p);

    // MFMA coarse convs -> concatenated output [B][NCC][128]
    k_coarse12m<<<gC, blk, 0, stream>>>(h12p, idx8s, w8s, Wfrag12,
                                        b1b, g1b, be1b, b2b, g2b, be2b, out);
    k_coarse3m<<<gC, blk, 0, stream>>>(h3p, idx8s, w8s, Wfrag3, b3b, g3b, be3b, out);
}